// Round 8
// baseline (645.024 us; speedup 1.0000x reference)
//
#include <hip/hip_runtime.h>
#include <math.h>

#define N_NODES 100000
#define N_EDGES 1600000
#define GEMM1_BLOCKS ((N_NODES + 63) / 64)        // 1563
#define FUSED_BLOCKS (GEMM1_BLOCKS * 5)           // 7815: 1563 gemm + 6252 link

typedef __attribute__((ext_vector_type(8))) short short8;    // 8 x bf16 bits
typedef __attribute__((ext_vector_type(4))) float floatx4;   // MFMA acc

__device__ __forceinline__ float lrelu(float v) {
    return (v > 0.f) ? v : 0.2f * v;
}

__device__ __forceinline__ unsigned short f2bf(float f) {
    unsigned int u = __float_as_uint(f);
    u += 0x7fff + ((u >> 16) & 1);   // round-to-nearest-even
    return (unsigned short)(u >> 16);
}

__device__ __forceinline__ float bflo(unsigned int u) { return __uint_as_float(u << 16); }
__device__ __forceinline__ float bfhi(unsigned int u) { return __uint_as_float(u & 0xffff0000u); }

// ---------------------------------------------------------------------------
// prep: swizzle W1/W2 into bf16 MFMA B-fragment order.
// ---------------------------------------------------------------------------
__global__ void prep_kernel(const float* __restrict__ W1, const float* __restrict__ W2,
                            unsigned short* __restrict__ w1b, unsigned short* __restrict__ w2b) {
    int idx = blockIdx.x * 256 + threadIdx.x;
    if (idx < 4096) {
        int lane = idx & 63;
        int ts = idx >> 6;
        int t = ts >> 3, ks = ts & 7;
        int quad = lane >> 4, l15 = lane & 15;
        int kbase = ks * 32 + quad * 8;
        unsigned short o[8];
        #pragma unroll
        for (int j = 0; j < 8; j++)
            o[j] = f2bf(W1[(size_t)(kbase + j) * 128 + t * 16 + l15]);
        uint4 pk;
        pk.x = o[0] | ((unsigned int)o[1] << 16);
        pk.y = o[2] | ((unsigned int)o[3] << 16);
        pk.z = o[4] | ((unsigned int)o[5] << 16);
        pk.w = o[6] | ((unsigned int)o[7] << 16);
        ((uint4*)w1b)[idx] = pk;
    } else if (idx < 4096 + 1024) {
        int idx2 = idx - 4096;
        int lane = idx2 & 63;
        int ts = idx2 >> 6;
        int t = ts >> 2, ks = ts & 3;
        int quad = lane >> 4, l15 = lane & 15;
        int kbase = ks * 32 + quad * 8;
        unsigned short o[8];
        #pragma unroll
        for (int j = 0; j < 8; j++)
            o[j] = f2bf(W2[(size_t)(kbase + j) * 64 + t * 16 + l15]);
        uint4 pk;
        pk.x = o[0] | ((unsigned int)o[1] << 16);
        pk.y = o[2] | ((unsigned int)o[3] << 16);
        pk.z = o[4] | ((unsigned int)o[5] << 16);
        pk.w = o[6] | ((unsigned int)o[7] << 16);
        ((uint4*)w2b)[idx2] = pk;
    }
}

// ---------------------------------------------------------------------------
// Fused GEMM1 (MFMA bf16) + linked-list build, roles INTERLEAVED (bid % 5):
// EXACT round-2 form (112 µs proven — best pairing per rounds 4/5/7).
// link: rec8[e] = {atomicExch(&head[dst], e), src}; head pre-memset -1.
// ---------------------------------------------------------------------------
__global__ void __launch_bounds__(256) gemm1_link_kernel(
        const float* __restrict__ x, const short8* __restrict__ w1b,
        const float* __restrict__ att_s, const float* __restrict__ att_d,
        unsigned short* __restrict__ h1b, float* __restrict__ a1s, float* __restrict__ a1d,
        const int* __restrict__ ei, int* __restrict__ head, int2* __restrict__ rec8) {
    const int bid = blockIdx.x;
    if (bid % 5 != 0) {
        int lid = bid - bid / 5 - 1;               // 0..6251
        int e = lid * 256 + threadIdx.x;
        if (e < N_EDGES) {
            int s = ei[e];
            int d = ei[N_EDGES + e];
            int old = atomicExch(&head[d], e);
            rec8[e] = make_int2(old, s);
        }
        return;
    }
    const int gid = bid / 5;                        // 0..1562
    const int lane = threadIdx.x & 63;
    const int wv = threadIdx.x >> 6;
    const int quad = lane >> 4;
    const int l15 = lane & 15;
    const int M = N_NODES;

    const int rowA = gid * 64 + wv * 16 + l15;
    const bool rowAok = rowA < M;
    const float4* xrow4 = (const float4*)(x + (size_t)rowA * 256);

    floatx4 acc[8];
    #pragma unroll
    for (int t = 0; t < 8; t++) acc[t] = (floatx4){0.f, 0.f, 0.f, 0.f};

    #pragma unroll
    for (int ks = 0; ks < 8; ks++) {
        float4 p0, p1;
        if (rowAok) {
            p0 = xrow4[ks * 8 + quad * 2];
            p1 = xrow4[ks * 8 + quad * 2 + 1];
        } else {
            p0 = make_float4(0.f, 0.f, 0.f, 0.f);
            p1 = p0;
        }
        short8 af;
        af[0] = (short)f2bf(p0.x); af[1] = (short)f2bf(p0.y);
        af[2] = (short)f2bf(p0.z); af[3] = (short)f2bf(p0.w);
        af[4] = (short)f2bf(p1.x); af[5] = (short)f2bf(p1.y);
        af[6] = (short)f2bf(p1.z); af[7] = (short)f2bf(p1.w);
        #pragma unroll
        for (int t = 0; t < 8; t++) {
            short8 bf = w1b[(t * 8 + ks) * 64 + lane];
            acc[t] = __builtin_amdgcn_mfma_f32_16x16x32_bf16(af, bf, acc[t], 0, 0, 0);
        }
    }

    // Epilogue: C layout col = l15, row = quad*4 + r (tile t == head t).
    const int rowC0 = gid * 64 + wv * 16 + quad * 4;
    #pragma unroll
    for (int t = 0; t < 8; t++) {
        float asw = att_s[t * 16 + l15];
        float adw = att_d[t * 16 + l15];
        #pragma unroll
        for (int r = 0; r < 4; r++) {
            int grow = rowC0 + r;
            float c = acc[t][r];
            if (grow < M) h1b[(size_t)grow * 128 + t * 16 + l15] = f2bf(c);
            float ps = c * asw;
            float pd = c * adw;
            ps += __shfl_xor(ps, 1, 64); ps += __shfl_xor(ps, 2, 64);
            ps += __shfl_xor(ps, 4, 64); ps += __shfl_xor(ps, 8, 64);
            pd += __shfl_xor(pd, 1, 64); pd += __shfl_xor(pd, 2, 64);
            pd += __shfl_xor(pd, 4, 64); pd += __shfl_xor(pd, 8, 64);
            if (l15 == 0 && grow < M) { a1s[grow * 8 + t] = ps; a1d[grow * 8 + t] = pd; }
        }
    }
}

// ---------------------------------------------------------------------------
// csr_agg1: FUSED csr_build + agg1. One wave per dst node walks its chain
// directly (rec8[e] is a 64-lane broadcast load); each discovered src
// immediately feeds the agg1 gathers (a1s + full h1b row), so the serial
// walk hides under gather traffic and csr_build's standalone window
// disappears. For agg2's later use, lane t keeps step-t's src in a register
// (2 regs cover deg<=128; P(deg>128 | Poisson(16)) ~ 0); after the walk a
// per-BLOCK atomicAdd allocates the csr row (25k block-atomics, not 100k
// wave-atomics, to stay under same-address atomic throughput) and one
// coalesced 64-lane store writes the row. Epilogue = agg1's (/denom, +b1,
// ELU, pack bf16 h2).
// ---------------------------------------------------------------------------
__global__ void __launch_bounds__(256) csr_agg1_kernel(
        const unsigned short* __restrict__ h1b, const float* __restrict__ a1s,
        const float* __restrict__ a1d, const int* __restrict__ head,
        const int2* __restrict__ rec8, int* __restrict__ rowstart,
        int* __restrict__ deg, int* __restrict__ counter, int* __restrict__ csr_src,
        const float* __restrict__ b1, unsigned int* __restrict__ h2b, int n) {
    const int lane = threadIdx.x & 63;
    const int wv = threadIdx.x >> 6;
    const int node = blockIdx.x * 4 + wv;
    const bool ok = node < n;
    const int h = lane >> 3;

    __shared__ int sd[4];

    const float ad = ok ? a1d[node * 8 + h] : 0.f;
    float l = 0.f, acc0 = 0.f, acc1 = 0.f;
    int mysrc0 = 0, mysrc1 = 0;
    int e = ok ? head[node] : -1;
    int t = 0;
    while (e >= 0) {
        int2 r = rec8[e];                          // broadcast: all lanes same addr
        int s = r.y;
        if (t == lane) mysrc0 = s;                 // reg-cache for csr replay
        if (t == lane + 64) mysrc1 = s;
        float as = a1s[s * 8 + h];
        unsigned int u = *(const unsigned int*)(h1b + (size_t)s * 128 + lane * 2);
        float ew = __expf(lrelu(as + ad));
        l += ew;
        acc0 += ew * bflo(u);
        acc1 += ew * bfhi(u);
        e = r.x;
        t++;
    }
    const int d = t;

    // per-block csr row allocation (4 waves -> 1 atomic)
    if (lane == 0) sd[wv] = d;
    __syncthreads();
    if (threadIdx.x == 0) {
        int t0 = sd[0], t1 = sd[1], t2 = sd[2], t3 = sd[3];
        int base = atomicAdd(counter, t0 + t1 + t2 + t3);
        sd[0] = base;
        sd[1] = base + t0;
        sd[2] = base + t0 + t1;
        sd[3] = base + t0 + t1 + t2;
    }
    __syncthreads();
    const int rs = sd[wv];

    if (ok) {
        if (lane == 0) { rowstart[node] = rs; deg[node] = d; }
        if (lane < d) csr_src[rs + lane] = mysrc0;            // coalesced
        if (lane + 64 < d) csr_src[rs + lane + 64] = mysrc1;

        float inv = 1.f / (l + 1e-16f);
        float v0 = acc0 * inv + b1[lane * 2];
        float v1 = acc1 * inv + b1[lane * 2 + 1];
        v0 = (v0 > 0.f) ? v0 : expm1f(v0);
        v1 = (v1 > 0.f) ? v1 : expm1f(v1);
        h2b[(size_t)node * 64 + lane] = (unsigned int)f2bf(v0) | ((unsigned int)f2bf(v1) << 16);
    }
}

// ---------------------------------------------------------------------------
// GEMM2 (MFMA bf16): t2b = bf16(h2[N,128] @ W2[128,64]); fused a2s/a2d dots.
// ---------------------------------------------------------------------------
__global__ void __launch_bounds__(256) gemm2_kernel(
        const short8* __restrict__ h2f, const short8* __restrict__ w2b,
        const float* __restrict__ att_s, const float* __restrict__ att_d,
        unsigned short* __restrict__ t2b, float* __restrict__ a2s, float* __restrict__ a2d,
        int n) {
    const int lane = threadIdx.x & 63;
    const int wv = threadIdx.x >> 6;
    const int quad = lane >> 4;
    const int l15 = lane & 15;

    const int rowA = blockIdx.x * 64 + wv * 16 + l15;
    const bool rowAok = rowA < n;

    floatx4 acc[4];
    #pragma unroll
    for (int t = 0; t < 4; t++) acc[t] = (floatx4){0.f, 0.f, 0.f, 0.f};

    #pragma unroll
    for (int ks = 0; ks < 4; ks++) {
        short8 af = {0, 0, 0, 0, 0, 0, 0, 0};
        if (rowAok) af = h2f[(size_t)rowA * 16 + ks * 4 + quad];
        #pragma unroll
        for (int t = 0; t < 4; t++) {
            short8 bf = w2b[(t * 4 + ks) * 64 + lane];
            acc[t] = __builtin_amdgcn_mfma_f32_16x16x32_bf16(af, bf, acc[t], 0, 0, 0);
        }
    }

    const int rowC0 = blockIdx.x * 64 + wv * 16 + quad * 4;
    float asw[4], adw[4];
    #pragma unroll
    for (int t = 0; t < 4; t++) {
        asw[t] = att_s[t * 16 + l15];
        adw[t] = att_d[t * 16 + l15];
    }
    #pragma unroll
    for (int r = 0; r < 4; r++) {
        int grow = rowC0 + r;
        bool ok = grow < n;
        float ps = 0.f, pd = 0.f;
        #pragma unroll
        for (int t = 0; t < 4; t++) {
            float c = acc[t][r];
            if (ok) t2b[(size_t)grow * 64 + t * 16 + l15] = f2bf(c);
            ps += c * asw[t];
            pd += c * adw[t];
        }
        ps += __shfl_xor(ps, 1, 64); ps += __shfl_xor(ps, 2, 64);
        ps += __shfl_xor(ps, 4, 64); ps += __shfl_xor(ps, 8, 64);
        pd += __shfl_xor(pd, 1, 64); pd += __shfl_xor(pd, 2, 64);
        pd += __shfl_xor(pd, 4, 64); pd += __shfl_xor(pd, 8, 64);
        if (l15 == 0 && ok) { a2s[grow] = ps; a2d[grow] = pd; }
    }
}

// ---------------------------------------------------------------------------
// agg2: one wave per dst node over CSR. 8-way unrolled (round-6 form).
// Fused bias + log_softmax across the 64 lanes.
// ---------------------------------------------------------------------------
__global__ void __launch_bounds__(256) agg2_kernel(
        const unsigned short* __restrict__ t2b, const float* __restrict__ a2s,
        const float* __restrict__ a2d, const int* __restrict__ rowstart,
        const int* __restrict__ deg, const int* __restrict__ csr_src,
        const float* __restrict__ b2, float* __restrict__ out, int n) {
    const int lane = threadIdx.x & 63;
    const int node = blockIdx.x * 4 + (threadIdx.x >> 6);
    if (node >= n) return;
    const int start = rowstart[node];
    const int d = deg[node];
    const float ad = a2d[node];
    float l = 0.f, acc = 0.f;
    int i = 0;
    for (; i + 8 <= d; i += 8) {
        int s[8];
        float as[8];
        unsigned short u[8];
        #pragma unroll
        for (int k = 0; k < 8; k++) s[k] = csr_src[start + i + k];
        #pragma unroll
        for (int k = 0; k < 8; k++) as[k] = a2s[s[k]];
        #pragma unroll
        for (int k = 0; k < 8; k++) u[k] = t2b[(size_t)s[k] * 64 + lane];
        #pragma unroll
        for (int k = 0; k < 8; k++) {
            float e = __expf(lrelu(as[k] + ad));
            l += e;
            acc += e * __uint_as_float(((unsigned int)u[k]) << 16);
        }
    }
    for (; i + 4 <= d; i += 4) {
        int s[4];
        float as[4];
        unsigned short u[4];
        #pragma unroll
        for (int k = 0; k < 4; k++) s[k] = csr_src[start + i + k];
        #pragma unroll
        for (int k = 0; k < 4; k++) as[k] = a2s[s[k]];
        #pragma unroll
        for (int k = 0; k < 4; k++) u[k] = t2b[(size_t)s[k] * 64 + lane];
        #pragma unroll
        for (int k = 0; k < 4; k++) {
            float e = __expf(lrelu(as[k] + ad));
            l += e;
            acc += e * __uint_as_float(((unsigned int)u[k]) << 16);
        }
    }
    for (; i < d; i++) {
        int s0 = csr_src[start + i];
        float as0 = a2s[s0];
        unsigned short u0 = t2b[(size_t)s0 * 64 + lane];
        float e0 = __expf(lrelu(as0 + ad));
        l += e0;
        acc += e0 * __uint_as_float(((unsigned int)u0) << 16);
    }
    float v = acc / (l + 1e-16f) + b2[lane];
    float mx = v;
    #pragma unroll
    for (int off = 32; off >= 1; off >>= 1) mx = fmaxf(mx, __shfl_xor(mx, off, 64));
    float ex = expf(v - mx);
    float s2 = ex;
    #pragma unroll
    for (int off = 32; off >= 1; off >>= 1) s2 += __shfl_xor(s2, off, 64);
    out[(size_t)node * 64 + lane] = v - mx - logf(s2);
}

// ---------------------------------------------------------------------------

extern "C" void kernel_launch(void* const* d_in, const int* in_sizes, int n_in,
                              void* d_out, int out_size, void* d_ws, size_t ws_size,
                              hipStream_t stream) {
    const float* x     = (const float*)d_in[0];
    const int*   ei    = (const int*)d_in[1];
    const float* W1    = (const float*)d_in[2];
    const float* att1s = (const float*)d_in[3];
    const float* att1d = (const float*)d_in[4];
    const float* b1    = (const float*)d_in[5];
    const float* W2    = (const float*)d_in[6];
    const float* att2s = (const float*)d_in[7];
    const float* att2d = (const float*)d_in[8];
    const float* b2    = (const float*)d_in[9];
    float* out = (float*)d_out;

    const int N = N_NODES, E = N_EDGES;

    char* p = (char*)d_ws;
    auto take = [&](size_t bytes) {
        char* r = p;
        p += (bytes + 255) & ~(size_t)255;
        return (void*)r;
    };
    int*            head     = (int*)take((size_t)N * 4);
    int*            deg      = (int*)take((size_t)N * 4);
    int*            rowstart = (int*)take((size_t)N * 4);
    int*            counter  = (int*)take(256);
    int2*           rec8     = (int2*)take((size_t)E * 8);
    int*            csr_src  = (int*)take((size_t)E * 4);
    unsigned short* w1b      = (unsigned short*)take(64 * 64 * 16);           // 64 KB
    unsigned short* w2b      = (unsigned short*)take(16 * 64 * 16);           // 16 KB
    unsigned short* h1b      = (unsigned short*)take((size_t)N * 128 * 2);    // bf16
    float*          a1s      = (float*)take((size_t)N * 8 * 4);               // reused a2s
    float*          a1d      = (float*)take((size_t)N * 8 * 4);               // reused a2d
    unsigned int*   h2b      = (unsigned int*)take((size_t)N * 64 * 4);       // packed bf16
    unsigned short* t2b      = (unsigned short*)take((size_t)N * 64 * 2);     // bf16
    float* a2s = a1s;
    float* a2d = a1d;

    hipMemsetAsync(head, 0xFF, (size_t)N * 4, stream);   // -1 sentinels
    hipMemsetAsync(counter, 0, 4, stream);

    prep_kernel<<<20, 256, 0, stream>>>(W1, W2, w1b, w2b);
    gemm1_link_kernel<<<FUSED_BLOCKS, 256, 0, stream>>>(
        x, (const short8*)w1b, att1s, att1d, h1b, a1s, a1d, ei, head, rec8);
    csr_agg1_kernel<<<(N + 3) / 4, 256, 0, stream>>>(
        h1b, a1s, a1d, head, rec8, rowstart, deg, counter, csr_src, b1, h2b, N);
    gemm2_kernel<<<(N + 63) / 64, 256, 0, stream>>>((const short8*)h2b, (const short8*)w2b,
                                                    att2s, att2d, t2b, a2s, a2d, N);
    agg2_kernel<<<(N + 3) / 4, 256, 0, stream>>>(t2b, a2s, a2d, rowstart, deg, csr_src,
                                                 b2, out, N);
}

// Round 9
// 477.487 us; speedup vs baseline: 1.3509x; 1.3509x over previous
//
#include <hip/hip_runtime.h>
#include <math.h>

#define N_NODES 100000
#define N_EDGES 1600000
#define GEMM1_BLOCKS ((N_NODES + 63) / 64)        // 1563
#define FUSED_BLOCKS (GEMM1_BLOCKS * 5)           // 7815: 1563 gemm + 6252 link
#define KCHAIN 24

typedef __attribute__((ext_vector_type(8))) short short8;    // 8 x bf16 bits
typedef __attribute__((ext_vector_type(4))) float floatx4;   // MFMA acc

__device__ __forceinline__ float lrelu(float v) {
    return (v > 0.f) ? v : 0.2f * v;
}

__device__ __forceinline__ unsigned short f2bf(float f) {
    unsigned int u = __float_as_uint(f);
    u += 0x7fff + ((u >> 16) & 1);   // round-to-nearest-even
    return (unsigned short)(u >> 16);
}

__device__ __forceinline__ float bflo(unsigned int u) { return __uint_as_float(u << 16); }
__device__ __forceinline__ float bfhi(unsigned int u) { return __uint_as_float(u & 0xffff0000u); }
__device__ __forceinline__ float bfs(unsigned short s) { return __uint_as_float(((unsigned int)s) << 16); }

// ---------------------------------------------------------------------------
// prep: swizzle W1 into bf16 MFMA B-fragment order (idx<4096); convert W2 to
// plain bf16 row-major [128][64] for the fused agg1 GEMV (idx 4096..6143).
// ---------------------------------------------------------------------------
__global__ void prep_kernel(const float* __restrict__ W1, const float* __restrict__ W2,
                            unsigned short* __restrict__ w1b, unsigned short* __restrict__ w2p) {
    int idx = blockIdx.x * 256 + threadIdx.x;
    if (idx < 4096) {
        int lane = idx & 63;
        int ts = idx >> 6;
        int t = ts >> 3, ks = ts & 7;
        int quad = lane >> 4, l15 = lane & 15;
        int kbase = ks * 32 + quad * 8;
        unsigned short o[8];
        #pragma unroll
        for (int j = 0; j < 8; j++)
            o[j] = f2bf(W1[(size_t)(kbase + j) * 128 + t * 16 + l15]);
        uint4 pk;
        pk.x = o[0] | ((unsigned int)o[1] << 16);
        pk.y = o[2] | ((unsigned int)o[3] << 16);
        pk.z = o[4] | ((unsigned int)o[5] << 16);
        pk.w = o[6] | ((unsigned int)o[7] << 16);
        ((uint4*)w1b)[idx] = pk;
    } else if (idx < 4096 + 2048) {
        int idx2 = idx - 4096;                       // 4 consecutive W2 elems
        unsigned short o0 = f2bf(W2[idx2 * 4]);
        unsigned short o1 = f2bf(W2[idx2 * 4 + 1]);
        unsigned short o2 = f2bf(W2[idx2 * 4 + 2]);
        unsigned short o3 = f2bf(W2[idx2 * 4 + 3]);
        uint2 pk;
        pk.x = o0 | ((unsigned int)o1 << 16);
        pk.y = o2 | ((unsigned int)o3 << 16);
        ((uint2*)w2p)[idx2] = pk;
    }
}

// ---------------------------------------------------------------------------
// Fused GEMM1 (MFMA bf16) + linked-list build, roles INTERLEAVED (bid % 5):
// EXACT round-2 form (112 µs proven).
// link: rec8[e] = {atomicExch(&head[dst], e), src}; head pre-memset -1.
// ---------------------------------------------------------------------------
__global__ void __launch_bounds__(256) gemm1_link_kernel(
        const float* __restrict__ x, const short8* __restrict__ w1b,
        const float* __restrict__ att_s, const float* __restrict__ att_d,
        unsigned short* __restrict__ h1b, float* __restrict__ a1s, float* __restrict__ a1d,
        const int* __restrict__ ei, int* __restrict__ head, int2* __restrict__ rec8) {
    const int bid = blockIdx.x;
    if (bid % 5 != 0) {
        int lid = bid - bid / 5 - 1;               // 0..6251
        int e = lid * 256 + threadIdx.x;
        if (e < N_EDGES) {
            int s = ei[e];
            int d = ei[N_EDGES + e];
            int old = atomicExch(&head[d], e);
            rec8[e] = make_int2(old, s);
        }
        return;
    }
    const int gid = bid / 5;                        // 0..1562
    const int lane = threadIdx.x & 63;
    const int wv = threadIdx.x >> 6;
    const int quad = lane >> 4;
    const int l15 = lane & 15;
    const int M = N_NODES;

    const int rowA = gid * 64 + wv * 16 + l15;
    const bool rowAok = rowA < M;
    const float4* xrow4 = (const float4*)(x + (size_t)rowA * 256);

    floatx4 acc[8];
    #pragma unroll
    for (int t = 0; t < 8; t++) acc[t] = (floatx4){0.f, 0.f, 0.f, 0.f};

    #pragma unroll
    for (int ks = 0; ks < 8; ks++) {
        float4 p0, p1;
        if (rowAok) {
            p0 = xrow4[ks * 8 + quad * 2];
            p1 = xrow4[ks * 8 + quad * 2 + 1];
        } else {
            p0 = make_float4(0.f, 0.f, 0.f, 0.f);
            p1 = p0;
        }
        short8 af;
        af[0] = (short)f2bf(p0.x); af[1] = (short)f2bf(p0.y);
        af[2] = (short)f2bf(p0.z); af[3] = (short)f2bf(p0.w);
        af[4] = (short)f2bf(p1.x); af[5] = (short)f2bf(p1.y);
        af[6] = (short)f2bf(p1.z); af[7] = (short)f2bf(p1.w);
        #pragma unroll
        for (int t = 0; t < 8; t++) {
            short8 bf = w1b[(t * 8 + ks) * 64 + lane];
            acc[t] = __builtin_amdgcn_mfma_f32_16x16x32_bf16(af, bf, acc[t], 0, 0, 0);
        }
    }

    // Epilogue: C layout col = l15, row = quad*4 + r (tile t == head t).
    const int rowC0 = gid * 64 + wv * 16 + quad * 4;
    #pragma unroll
    for (int t = 0; t < 8; t++) {
        float asw = att_s[t * 16 + l15];
        float adw = att_d[t * 16 + l15];
        #pragma unroll
        for (int r = 0; r < 4; r++) {
            int grow = rowC0 + r;
            float c = acc[t][r];
            if (grow < M) h1b[(size_t)grow * 128 + t * 16 + l15] = f2bf(c);
            float ps = c * asw;
            float pd = c * adw;
            ps += __shfl_xor(ps, 1, 64); ps += __shfl_xor(ps, 2, 64);
            ps += __shfl_xor(ps, 4, 64); ps += __shfl_xor(ps, 8, 64);
            pd += __shfl_xor(pd, 1, 64); pd += __shfl_xor(pd, 2, 64);
            pd += __shfl_xor(pd, 4, 64); pd += __shfl_xor(pd, 8, 64);
            if (l15 == 0 && grow < M) { a1s[grow * 8 + t] = ps; a1d[grow * 8 + t] = pd; }
        }
    }
}

// ---------------------------------------------------------------------------
// csr_build: fused count_alloc + flatten (round-2/6 proven form).
// ---------------------------------------------------------------------------
__global__ void __launch_bounds__(256) csr_build_kernel(
        const int* __restrict__ head, const int2* __restrict__ rec8,
        int* __restrict__ rowstart, int* __restrict__ deg,
        int* __restrict__ counter, int* __restrict__ csr_src, int n) {
    int i = blockIdx.x * 256 + threadIdx.x;
    int lane = threadIdx.x & 63;
    int e = (i < n) ? head[i] : -1;
    int srcbuf[KCHAIN];
    int c = 0;
    #pragma unroll
    for (int k = 0; k < KCHAIN; k++) {
        srcbuf[k] = 0;
        if (e >= 0) {
            int2 r = rec8[e];
            srcbuf[k] = r.y;
            e = r.x;
            c++;
        }
    }
    int etail = e;                      // continue point for deg > KCHAIN
    while (e >= 0) {                    // count remainder
        e = ((const int*)rec8)[(size_t)e * 2];
        c++;
    }
    // wave inclusive scan of c -> exclusive offset
    int pre = c;
    #pragma unroll
    for (int off = 1; off < 64; off <<= 1) {
        int v = __shfl_up(pre, off, 64);
        if (lane >= off) pre += v;
    }
    int total = __shfl(pre, 63, 64);
    int base = 0;
    if (lane == 63) base = atomicAdd(counter, total);
    base = __shfl(base, 63, 64);
    if (i < n) {
        int rs = base + pre - c;
        rowstart[i] = rs;
        deg[i] = c;
        #pragma unroll
        for (int k = 0; k < KCHAIN; k++)
            if (k < c) csr_src[rs + k] = srcbuf[k];
        // overflow tail (lines are L1/L2-hot from the count loop)
        e = etail;
        int idx = rs + KCHAIN;
        while (e >= 0) {
            int2 r = rec8[e];
            csr_src[idx++] = r.y;
            e = r.x;
        }
    }
}

// ---------------------------------------------------------------------------
// agg1_gemm2: round-6 agg1 (8-way unrolled CSR gather, /denom, +b1, ELU)
// FUSED with the per-node 128x64 GEMV that was gemm2. The wave's h2 row
// (held in v0/v1 regs) goes to per-wave LDS; t2[lane] = sum_k h2[k]*W2[k][lane]
// with W2 cached in LDS as bf16 [k][lane] (conflict-free; h2 reads broadcast).
// Inline wave-reduce of a2s/a2d. Eliminates gemm2 kernel + h2b roundtrip.
// a2s/a2d are SEPARATE buffers (a1s/a1d still being read concurrently).
// ---------------------------------------------------------------------------
__global__ void __launch_bounds__(256) agg1_gemm2_kernel(
        const unsigned short* __restrict__ h1b, const float* __restrict__ a1s,
        const float* __restrict__ a1d, const int* __restrict__ rowstart,
        const int* __restrict__ deg, const int* __restrict__ csr_src,
        const float* __restrict__ b1, const unsigned short* __restrict__ w2p,
        const float* __restrict__ att2s, const float* __restrict__ att2d,
        unsigned short* __restrict__ t2b, float* __restrict__ a2s,
        float* __restrict__ a2d, int n) {
    __shared__ unsigned short w2s[128 * 64];   // 16 KB bf16 W2, [k][c]
    __shared__ float h2s[4][128];              // per-wave h2 row

    // cooperative W2 load: 16 KB / 256 threads = 64 B = 4 x uint4
    #pragma unroll
    for (int i = 0; i < 4; i++)
        ((uint4*)w2s)[threadIdx.x + i * 256] = ((const uint4*)w2p)[threadIdx.x + i * 256];
    __syncthreads();

    const int lane = threadIdx.x & 63;
    const int wv = threadIdx.x >> 6;
    const int node = blockIdx.x * 4 + wv;
    if (node >= n) return;                     // N%4==0: never splits a block
    const int h = lane >> 3;
    const int start = rowstart[node];
    const int d = deg[node];
    const float ad = a1d[node * 8 + h];
    float l = 0.f, acc0 = 0.f, acc1 = 0.f;
    int i = 0;
    for (; i + 8 <= d; i += 8) {
        int s[8];
        float as[8];
        unsigned int u[8];
        #pragma unroll
        for (int k = 0; k < 8; k++) s[k] = csr_src[start + i + k];
        #pragma unroll
        for (int k = 0; k < 8; k++) as[k] = a1s[s[k] * 8 + h];
        #pragma unroll
        for (int k = 0; k < 8; k++)
            u[k] = *(const unsigned int*)(h1b + (size_t)s[k] * 128 + lane * 2);
        #pragma unroll
        for (int k = 0; k < 8; k++) {
            float e = __expf(lrelu(as[k] + ad));
            l += e;
            acc0 += e * bflo(u[k]);
            acc1 += e * bfhi(u[k]);
        }
    }
    for (; i + 4 <= d; i += 4) {
        int s[4];
        float as[4];
        unsigned int u[4];
        #pragma unroll
        for (int k = 0; k < 4; k++) s[k] = csr_src[start + i + k];
        #pragma unroll
        for (int k = 0; k < 4; k++) as[k] = a1s[s[k] * 8 + h];
        #pragma unroll
        for (int k = 0; k < 4; k++)
            u[k] = *(const unsigned int*)(h1b + (size_t)s[k] * 128 + lane * 2);
        #pragma unroll
        for (int k = 0; k < 4; k++) {
            float e = __expf(lrelu(as[k] + ad));
            l += e;
            acc0 += e * bflo(u[k]);
            acc1 += e * bfhi(u[k]);
        }
    }
    for (; i < d; i++) {
        int s0 = csr_src[start + i];
        float as0 = a1s[s0 * 8 + h];
        unsigned int u0 = *(const unsigned int*)(h1b + (size_t)s0 * 128 + lane * 2);
        float e0 = __expf(lrelu(as0 + ad));
        l += e0;
        acc0 += e0 * bflo(u0);
        acc1 += e0 * bfhi(u0);
    }
    float inv = 1.f / (l + 1e-16f);
    float v0 = acc0 * inv + b1[lane * 2];
    float v1 = acc1 * inv + b1[lane * 2 + 1];
    v0 = (v0 > 0.f) ? v0 : expm1f(v0);
    v1 = (v1 > 0.f) ? v1 : expm1f(v1);

    // ---- fused GEMV: t2[lane] = sum_k h2[k] * W2[k][lane] ----
    h2s[wv][lane * 2] = v0;
    h2s[wv][lane * 2 + 1] = v1;                // wave-synchronous: no barrier
    float t2 = 0.f;
    #pragma unroll
    for (int k = 0; k < 128; k += 2) {
        float hk0 = h2s[wv][k];
        float hk1 = h2s[wv][k + 1];
        t2 += hk0 * bfs(w2s[k * 64 + lane]) + hk1 * bfs(w2s[(k + 1) * 64 + lane]);
    }
    t2b[(size_t)node * 64 + lane] = f2bf(t2);
    float ps = t2 * att2s[lane];
    float pd = t2 * att2d[lane];
    #pragma unroll
    for (int off = 32; off >= 1; off >>= 1) {
        ps += __shfl_xor(ps, off, 64);
        pd += __shfl_xor(pd, off, 64);
    }
    if (lane == 0) { a2s[node] = ps; a2d[node] = pd; }
}

// ---------------------------------------------------------------------------
// agg2: one wave per dst node over CSR. 8-way unrolled (round-6 form).
// Fused bias + log_softmax across the 64 lanes.
// ---------------------------------------------------------------------------
__global__ void __launch_bounds__(256) agg2_kernel(
        const unsigned short* __restrict__ t2b, const float* __restrict__ a2s,
        const float* __restrict__ a2d, const int* __restrict__ rowstart,
        const int* __restrict__ deg, const int* __restrict__ csr_src,
        const float* __restrict__ b2, float* __restrict__ out, int n) {
    const int lane = threadIdx.x & 63;
    const int node = blockIdx.x * 4 + (threadIdx.x >> 6);
    if (node >= n) return;
    const int start = rowstart[node];
    const int d = deg[node];
    const float ad = a2d[node];
    float l = 0.f, acc = 0.f;
    int i = 0;
    for (; i + 8 <= d; i += 8) {
        int s[8];
        float as[8];
        unsigned short u[8];
        #pragma unroll
        for (int k = 0; k < 8; k++) s[k] = csr_src[start + i + k];
        #pragma unroll
        for (int k = 0; k < 8; k++) as[k] = a2s[s[k]];
        #pragma unroll
        for (int k = 0; k < 8; k++) u[k] = t2b[(size_t)s[k] * 64 + lane];
        #pragma unroll
        for (int k = 0; k < 8; k++) {
            float e = __expf(lrelu(as[k] + ad));
            l += e;
            acc += e * bfs(u[k]);
        }
    }
    for (; i + 4 <= d; i += 4) {
        int s[4];
        float as[4];
        unsigned short u[4];
        #pragma unroll
        for (int k = 0; k < 4; k++) s[k] = csr_src[start + i + k];
        #pragma unroll
        for (int k = 0; k < 4; k++) as[k] = a2s[s[k]];
        #pragma unroll
        for (int k = 0; k < 4; k++) u[k] = t2b[(size_t)s[k] * 64 + lane];
        #pragma unroll
        for (int k = 0; k < 4; k++) {
            float e = __expf(lrelu(as[k] + ad));
            l += e;
            acc += e * bfs(u[k]);
        }
    }
    for (; i < d; i++) {
        int s0 = csr_src[start + i];
        float as0 = a2s[s0];
        unsigned short u0 = t2b[(size_t)s0 * 64 + lane];
        float e0 = __expf(lrelu(as0 + ad));
        l += e0;
        acc += e0 * bfs(u0);
    }
    float v = acc / (l + 1e-16f) + b2[lane];
    float mx = v;
    #pragma unroll
    for (int off = 32; off >= 1; off >>= 1) mx = fmaxf(mx, __shfl_xor(mx, off, 64));
    float ex = expf(v - mx);
    float s2 = ex;
    #pragma unroll
    for (int off = 32; off >= 1; off >>= 1) s2 += __shfl_xor(s2, off, 64);
    out[(size_t)node * 64 + lane] = v - mx - logf(s2);
}

// ---------------------------------------------------------------------------

extern "C" void kernel_launch(void* const* d_in, const int* in_sizes, int n_in,
                              void* d_out, int out_size, void* d_ws, size_t ws_size,
                              hipStream_t stream) {
    const float* x     = (const float*)d_in[0];
    const int*   ei    = (const int*)d_in[1];
    const float* W1    = (const float*)d_in[2];
    const float* att1s = (const float*)d_in[3];
    const float* att1d = (const float*)d_in[4];
    const float* b1    = (const float*)d_in[5];
    const float* W2    = (const float*)d_in[6];
    const float* att2s = (const float*)d_in[7];
    const float* att2d = (const float*)d_in[8];
    const float* b2    = (const float*)d_in[9];
    float* out = (float*)d_out;

    const int N = N_NODES, E = N_EDGES;

    char* p = (char*)d_ws;
    auto take = [&](size_t bytes) {
        char* r = p;
        p += (bytes + 255) & ~(size_t)255;
        return (void*)r;
    };
    int*            head     = (int*)take((size_t)N * 4);
    int*            deg      = (int*)take((size_t)N * 4);
    int*            rowstart = (int*)take((size_t)N * 4);
    int*            counter  = (int*)take(256);
    int2*           rec8     = (int2*)take((size_t)E * 8);
    int*            csr_src  = (int*)take((size_t)E * 4);
    unsigned short* w1b      = (unsigned short*)take(64 * 64 * 16);           // 64 KB
    unsigned short* w2p      = (unsigned short*)take(128 * 64 * 2);           // 16 KB
    unsigned short* h1b      = (unsigned short*)take((size_t)N * 128 * 2);    // bf16
    float*          a1s      = (float*)take((size_t)N * 8 * 4);
    float*          a1d      = (float*)take((size_t)N * 8 * 4);
    unsigned short* t2b      = (unsigned short*)take((size_t)N * 64 * 2);     // bf16
    float*          a2s      = (float*)take((size_t)N * 4);                   // own buffer!
    float*          a2d      = (float*)take((size_t)N * 4);                   // own buffer!

    hipMemsetAsync(head, 0xFF, (size_t)N * 4, stream);   // -1 sentinels
    hipMemsetAsync(counter, 0, 4, stream);

    prep_kernel<<<24, 256, 0, stream>>>(W1, W2, w1b, w2p);
    gemm1_link_kernel<<<FUSED_BLOCKS, 256, 0, stream>>>(
        x, (const short8*)w1b, att1s, att1d, h1b, a1s, a1d, ei, head, rec8);
    csr_build_kernel<<<(N + 255) / 256, 256, 0, stream>>>(head, rec8, rowstart, deg,
                                                          counter, csr_src, N);
    agg1_gemm2_kernel<<<(N + 3) / 4, 256, 0, stream>>>(
        h1b, a1s, a1d, rowstart, deg, csr_src, b1, w2p, att2s, att2d,
        t2b, a2s, a2d, N);
    agg2_kernel<<<(N + 3) / 4, 256, 0, stream>>>(t2b, a2s, a2d, rowstart, deg, csr_src,
                                                 b2, out, N);
}

// Round 10
// 446.665 us; speedup vs baseline: 1.4441x; 1.0690x over previous
//
#include <hip/hip_runtime.h>
#include <math.h>

#define N_NODES 100000
#define N_EDGES 1600000
#define GEMM1_BLOCKS ((N_NODES + 63) / 64)        // 1563
#define FUSED_BLOCKS (GEMM1_BLOCKS * 5)           // 7815: 1563 gemm + 6252 link
#define KC2 16                                    // per-chain reg cache (dual chains)

typedef __attribute__((ext_vector_type(8))) short short8;    // 8 x bf16 bits
typedef __attribute__((ext_vector_type(4))) float floatx4;   // MFMA acc

__device__ __forceinline__ float lrelu(float v) {
    return (v > 0.f) ? v : 0.2f * v;
}

__device__ __forceinline__ unsigned short f2bf(float f) {
    unsigned int u = __float_as_uint(f);
    u += 0x7fff + ((u >> 16) & 1);   // round-to-nearest-even
    return (unsigned short)(u >> 16);
}

__device__ __forceinline__ float bflo(unsigned int u) { return __uint_as_float(u << 16); }
__device__ __forceinline__ float bfhi(unsigned int u) { return __uint_as_float(u & 0xffff0000u); }
__device__ __forceinline__ float bfs(unsigned short s) { return __uint_as_float(((unsigned int)s) << 16); }

// ---------------------------------------------------------------------------
// prep: swizzle W1/W2 into bf16 MFMA B-fragment order.
// ---------------------------------------------------------------------------
__global__ void prep_kernel(const float* __restrict__ W1, const float* __restrict__ W2,
                            unsigned short* __restrict__ w1b, unsigned short* __restrict__ w2b) {
    int idx = blockIdx.x * 256 + threadIdx.x;
    if (idx < 4096) {
        int lane = idx & 63;
        int ts = idx >> 6;
        int t = ts >> 3, ks = ts & 7;
        int quad = lane >> 4, l15 = lane & 15;
        int kbase = ks * 32 + quad * 8;
        unsigned short o[8];
        #pragma unroll
        for (int j = 0; j < 8; j++)
            o[j] = f2bf(W1[(size_t)(kbase + j) * 128 + t * 16 + l15]);
        uint4 pk;
        pk.x = o[0] | ((unsigned int)o[1] << 16);
        pk.y = o[2] | ((unsigned int)o[3] << 16);
        pk.z = o[4] | ((unsigned int)o[5] << 16);
        pk.w = o[6] | ((unsigned int)o[7] << 16);
        ((uint4*)w1b)[idx] = pk;
    } else if (idx < 4096 + 1024) {
        int idx2 = idx - 4096;
        int lane = idx2 & 63;
        int ts = idx2 >> 6;
        int t = ts >> 2, ks = ts & 3;
        int quad = lane >> 4, l15 = lane & 15;
        int kbase = ks * 32 + quad * 8;
        unsigned short o[8];
        #pragma unroll
        for (int j = 0; j < 8; j++)
            o[j] = f2bf(W2[(size_t)(kbase + j) * 64 + t * 16 + l15]);
        uint4 pk;
        pk.x = o[0] | ((unsigned int)o[1] << 16);
        pk.y = o[2] | ((unsigned int)o[3] << 16);
        pk.z = o[4] | ((unsigned int)o[5] << 16);
        pk.w = o[6] | ((unsigned int)o[7] << 16);
        ((uint4*)w2b)[idx2] = pk;
    }
}

// ---------------------------------------------------------------------------
// Fused GEMM1 (MFMA bf16) + linked-list build, roles INTERLEAVED (bid % 5):
// round-2 proven form, except DUAL-HEAD chains: head[2*dst + (e&1)] — two
// independent ~8-long chains per node so csr_build's serial walk halves.
// Same atomic count/traffic. head pre-memset -1 (2N ints).
// ---------------------------------------------------------------------------
__global__ void __launch_bounds__(256) gemm1_link_kernel(
        const float* __restrict__ x, const short8* __restrict__ w1b,
        const float* __restrict__ att_s, const float* __restrict__ att_d,
        unsigned short* __restrict__ h1b, float* __restrict__ a1s, float* __restrict__ a1d,
        const int* __restrict__ ei, int* __restrict__ head, int2* __restrict__ rec8) {
    const int bid = blockIdx.x;
    if (bid % 5 != 0) {
        int lid = bid - bid / 5 - 1;               // 0..6251
        int e = lid * 256 + threadIdx.x;
        if (e < N_EDGES) {
            int s = ei[e];
            int d = ei[N_EDGES + e];
            int old = atomicExch(&head[d * 2 + (e & 1)], e);
            rec8[e] = make_int2(old, s);
        }
        return;
    }
    const int gid = bid / 5;                        // 0..1562
    const int lane = threadIdx.x & 63;
    const int wv = threadIdx.x >> 6;
    const int quad = lane >> 4;
    const int l15 = lane & 15;
    const int M = N_NODES;

    const int rowA = gid * 64 + wv * 16 + l15;
    const bool rowAok = rowA < M;
    const float4* xrow4 = (const float4*)(x + (size_t)rowA * 256);

    floatx4 acc[8];
    #pragma unroll
    for (int t = 0; t < 8; t++) acc[t] = (floatx4){0.f, 0.f, 0.f, 0.f};

    #pragma unroll
    for (int ks = 0; ks < 8; ks++) {
        float4 p0, p1;
        if (rowAok) {
            p0 = xrow4[ks * 8 + quad * 2];
            p1 = xrow4[ks * 8 + quad * 2 + 1];
        } else {
            p0 = make_float4(0.f, 0.f, 0.f, 0.f);
            p1 = p0;
        }
        short8 af;
        af[0] = (short)f2bf(p0.x); af[1] = (short)f2bf(p0.y);
        af[2] = (short)f2bf(p0.z); af[3] = (short)f2bf(p0.w);
        af[4] = (short)f2bf(p1.x); af[5] = (short)f2bf(p1.y);
        af[6] = (short)f2bf(p1.z); af[7] = (short)f2bf(p1.w);
        #pragma unroll
        for (int t = 0; t < 8; t++) {
            short8 bf = w1b[(t * 8 + ks) * 64 + lane];
            acc[t] = __builtin_amdgcn_mfma_f32_16x16x32_bf16(af, bf, acc[t], 0, 0, 0);
        }
    }

    // Epilogue: C layout col = l15, row = quad*4 + r (tile t == head t).
    const int rowC0 = gid * 64 + wv * 16 + quad * 4;
    #pragma unroll
    for (int t = 0; t < 8; t++) {
        float asw = att_s[t * 16 + l15];
        float adw = att_d[t * 16 + l15];
        #pragma unroll
        for (int r = 0; r < 4; r++) {
            int grow = rowC0 + r;
            float c = acc[t][r];
            if (grow < M) h1b[(size_t)grow * 128 + t * 16 + l15] = f2bf(c);
            float ps = c * asw;
            float pd = c * adw;
            ps += __shfl_xor(ps, 1, 64); ps += __shfl_xor(ps, 2, 64);
            ps += __shfl_xor(ps, 4, 64); ps += __shfl_xor(ps, 8, 64);
            pd += __shfl_xor(pd, 1, 64); pd += __shfl_xor(pd, 2, 64);
            pd += __shfl_xor(pd, 4, 64); pd += __shfl_xor(pd, 8, 64);
            if (l15 == 0 && grow < M) { a1s[grow * 8 + t] = ps; a1d[grow * 8 + t] = pd; }
        }
    }
}

// ---------------------------------------------------------------------------
// csr_build: fused count+flatten over DUAL chains walked interleaved — two
// independent serial load chains per lane (2x MLP, half the critical path of
// the single-chain walk that was ~105us). First KC2 srcs of each chain are
// reg-cached (static indexing); overflow (P~0.3%/chain) re-walks L2-hot tail.
// Row layout: [chain0 items..., chain1 items...] — a permutation of the old
// order (FP-sum reorder only).
// ---------------------------------------------------------------------------
__global__ void __launch_bounds__(256) csr_build_kernel(
        const int* __restrict__ head, const int2* __restrict__ rec8,
        int* __restrict__ rowstart, int* __restrict__ deg,
        int* __restrict__ counter, int* __restrict__ csr_src, int n) {
    int i = blockIdx.x * 256 + threadIdx.x;
    int lane = threadIdx.x & 63;
    int e0 = (i < n) ? head[i * 2] : -1;
    int e1 = (i < n) ? head[i * 2 + 1] : -1;
    int sb0[KC2], sb1[KC2];
    int c0 = 0, c1 = 0;
    #pragma unroll
    for (int k = 0; k < KC2; k++) {
        sb0[k] = 0;
        sb1[k] = 0;
        if (e0 >= 0) {
            int2 r = rec8[e0];
            sb0[k] = r.y;
            e0 = r.x;
            c0++;
        }
        if (e1 >= 0) {
            int2 r = rec8[e1];
            sb1[k] = r.y;
            e1 = r.x;
            c1++;
        }
    }
    int t0 = e0, t1 = e1;               // continue points for overflow
    while (e0 >= 0 || e1 >= 0) {        // count remainders (both chains live)
        if (e0 >= 0) { e0 = ((const int*)rec8)[(size_t)e0 * 2]; c0++; }
        if (e1 >= 0) { e1 = ((const int*)rec8)[(size_t)e1 * 2]; c1++; }
    }
    int c = c0 + c1;
    // wave inclusive scan of c -> exclusive offset
    int pre = c;
    #pragma unroll
    for (int off = 1; off < 64; off <<= 1) {
        int v = __shfl_up(pre, off, 64);
        if (lane >= off) pre += v;
    }
    int total = __shfl(pre, 63, 64);
    int base = 0;
    if (lane == 63) base = atomicAdd(counter, total);
    base = __shfl(base, 63, 64);
    if (i < n) {
        int rs = base + pre - c;
        rowstart[i] = rs;
        deg[i] = c;
        #pragma unroll
        for (int k = 0; k < KC2; k++)
            if (k < c0) csr_src[rs + k] = sb0[k];
        #pragma unroll
        for (int k = 0; k < KC2; k++)
            if (k < c1) csr_src[rs + c0 + k] = sb1[k];
        // overflow tails (lines are L1/L2-hot from the count loop)
        e0 = t0;
        int idx = rs + KC2;
        while (e0 >= 0) {
            int2 r = rec8[e0];
            csr_src[idx++] = r.y;
            e0 = r.x;
        }
        e1 = t1;
        idx = rs + c0 + KC2;
        while (e1 >= 0) {
            int2 r = rec8[e1];
            csr_src[idx++] = r.y;
            e1 = r.x;
        }
    }
}

// ---------------------------------------------------------------------------
// agg1: one wave per dst node over CSR. 8-way unrolled (round-6 form).
// ---------------------------------------------------------------------------
__global__ void __launch_bounds__(256) agg1_kernel(
        const unsigned short* __restrict__ h1b, const float* __restrict__ a1s,
        const float* __restrict__ a1d, const int* __restrict__ rowstart,
        const int* __restrict__ deg, const int* __restrict__ csr_src,
        const float* __restrict__ b1, unsigned int* __restrict__ h2b, int n) {
    const int lane = threadIdx.x & 63;
    const int node = blockIdx.x * 4 + (threadIdx.x >> 6);
    if (node >= n) return;
    const int h = lane >> 3;
    const int start = rowstart[node];
    const int d = deg[node];
    const float ad = a1d[node * 8 + h];
    float l = 0.f, acc0 = 0.f, acc1 = 0.f;
    int i = 0;
    for (; i + 8 <= d; i += 8) {
        int s[8];
        float as[8];
        unsigned int u[8];
        #pragma unroll
        for (int k = 0; k < 8; k++) s[k] = csr_src[start + i + k];
        #pragma unroll
        for (int k = 0; k < 8; k++) as[k] = a1s[s[k] * 8 + h];
        #pragma unroll
        for (int k = 0; k < 8; k++)
            u[k] = *(const unsigned int*)(h1b + (size_t)s[k] * 128 + lane * 2);
        #pragma unroll
        for (int k = 0; k < 8; k++) {
            float e = __expf(lrelu(as[k] + ad));
            l += e;
            acc0 += e * bflo(u[k]);
            acc1 += e * bfhi(u[k]);
        }
    }
    for (; i + 4 <= d; i += 4) {
        int s[4];
        float as[4];
        unsigned int u[4];
        #pragma unroll
        for (int k = 0; k < 4; k++) s[k] = csr_src[start + i + k];
        #pragma unroll
        for (int k = 0; k < 4; k++) as[k] = a1s[s[k] * 8 + h];
        #pragma unroll
        for (int k = 0; k < 4; k++)
            u[k] = *(const unsigned int*)(h1b + (size_t)s[k] * 128 + lane * 2);
        #pragma unroll
        for (int k = 0; k < 4; k++) {
            float e = __expf(lrelu(as[k] + ad));
            l += e;
            acc0 += e * bflo(u[k]);
            acc1 += e * bfhi(u[k]);
        }
    }
    for (; i < d; i++) {
        int s0 = csr_src[start + i];
        float as0 = a1s[s0 * 8 + h];
        unsigned int u0 = *(const unsigned int*)(h1b + (size_t)s0 * 128 + lane * 2);
        float e0 = __expf(lrelu(as0 + ad));
        l += e0;
        acc0 += e0 * bflo(u0);
        acc1 += e0 * bfhi(u0);
    }
    float inv = 1.f / (l + 1e-16f);
    float v0 = acc0 * inv + b1[lane * 2];
    float v1 = acc1 * inv + b1[lane * 2 + 1];
    v0 = (v0 > 0.f) ? v0 : expm1f(v0);
    v1 = (v1 > 0.f) ? v1 : expm1f(v1);
    h2b[(size_t)node * 64 + lane] = (unsigned int)f2bf(v0) | ((unsigned int)f2bf(v1) << 16);
}

// ---------------------------------------------------------------------------
// GEMM2 (MFMA bf16): t2b = bf16(h2[N,128] @ W2[128,64]); fused a2s/a2d dots.
// ---------------------------------------------------------------------------
__global__ void __launch_bounds__(256) gemm2_kernel(
        const short8* __restrict__ h2f, const short8* __restrict__ w2b,
        const float* __restrict__ att_s, const float* __restrict__ att_d,
        unsigned short* __restrict__ t2b, float* __restrict__ a2s, float* __restrict__ a2d,
        int n) {
    const int lane = threadIdx.x & 63;
    const int wv = threadIdx.x >> 6;
    const int quad = lane >> 4;
    const int l15 = lane & 15;

    const int rowA = blockIdx.x * 64 + wv * 16 + l15;
    const bool rowAok = rowA < n;

    floatx4 acc[4];
    #pragma unroll
    for (int t = 0; t < 4; t++) acc[t] = (floatx4){0.f, 0.f, 0.f, 0.f};

    #pragma unroll
    for (int ks = 0; ks < 4; ks++) {
        short8 af = {0, 0, 0, 0, 0, 0, 0, 0};
        if (rowAok) af = h2f[(size_t)rowA * 16 + ks * 4 + quad];
        #pragma unroll
        for (int t = 0; t < 4; t++) {
            short8 bf = w2b[(t * 4 + ks) * 64 + lane];
            acc[t] = __builtin_amdgcn_mfma_f32_16x16x32_bf16(af, bf, acc[t], 0, 0, 0);
        }
    }

    const int rowC0 = blockIdx.x * 64 + wv * 16 + quad * 4;
    float asw[4], adw[4];
    #pragma unroll
    for (int t = 0; t < 4; t++) {
        asw[t] = att_s[t * 16 + l15];
        adw[t] = att_d[t * 16 + l15];
    }
    #pragma unroll
    for (int r = 0; r < 4; r++) {
        int grow = rowC0 + r;
        bool ok = grow < n;
        float ps = 0.f, pd = 0.f;
        #pragma unroll
        for (int t = 0; t < 4; t++) {
            float c = acc[t][r];
            if (ok) t2b[(size_t)grow * 64 + t * 16 + l15] = f2bf(c);
            ps += c * asw[t];
            pd += c * adw[t];
        }
        ps += __shfl_xor(ps, 1, 64); ps += __shfl_xor(ps, 2, 64);
        ps += __shfl_xor(ps, 4, 64); ps += __shfl_xor(ps, 8, 64);
        pd += __shfl_xor(pd, 1, 64); pd += __shfl_xor(pd, 2, 64);
        pd += __shfl_xor(pd, 4, 64); pd += __shfl_xor(pd, 8, 64);
        if (l15 == 0 && ok) { a2s[grow] = ps; a2d[grow] = pd; }
    }
}

// ---------------------------------------------------------------------------
// agg2: one wave per dst node over CSR. 8-way unrolled (round-6 form).
// Fused bias + log_softmax across the 64 lanes.
// ---------------------------------------------------------------------------
__global__ void __launch_bounds__(256) agg2_kernel(
        const unsigned short* __restrict__ t2b, const float* __restrict__ a2s,
        const float* __restrict__ a2d, const int* __restrict__ rowstart,
        const int* __restrict__ deg, const int* __restrict__ csr_src,
        const float* __restrict__ b2, float* __restrict__ out, int n) {
    const int lane = threadIdx.x & 63;
    const int node = blockIdx.x * 4 + (threadIdx.x >> 6);
    if (node >= n) return;
    const int start = rowstart[node];
    const int d = deg[node];
    const float ad = a2d[node];
    float l = 0.f, acc = 0.f;
    int i = 0;
    for (; i + 8 <= d; i += 8) {
        int s[8];
        float as[8];
        unsigned short u[8];
        #pragma unroll
        for (int k = 0; k < 8; k++) s[k] = csr_src[start + i + k];
        #pragma unroll
        for (int k = 0; k < 8; k++) as[k] = a2s[s[k]];
        #pragma unroll
        for (int k = 0; k < 8; k++) u[k] = t2b[(size_t)s[k] * 64 + lane];
        #pragma unroll
        for (int k = 0; k < 8; k++) {
            float e = __expf(lrelu(as[k] + ad));
            l += e;
            acc += e * bfs(u[k]);
        }
    }
    for (; i + 4 <= d; i += 4) {
        int s[4];
        float as[4];
        unsigned short u[4];
        #pragma unroll
        for (int k = 0; k < 4; k++) s[k] = csr_src[start + i + k];
        #pragma unroll
        for (int k = 0; k < 4; k++) as[k] = a2s[s[k]];
        #pragma unroll
        for (int k = 0; k < 4; k++) u[k] = t2b[(size_t)s[k] * 64 + lane];
        #pragma unroll
        for (int k = 0; k < 4; k++) {
            float e = __expf(lrelu(as[k] + ad));
            l += e;
            acc += e * bfs(u[k]);
        }
    }
    for (; i < d; i++) {
        int s0 = csr_src[start + i];
        float as0 = a2s[s0];
        unsigned short u0 = t2b[(size_t)s0 * 64 + lane];
        float e0 = __expf(lrelu(as0 + ad));
        l += e0;
        acc += e0 * bfs(u0);
    }
    float v = acc / (l + 1e-16f) + b2[lane];
    float mx = v;
    #pragma unroll
    for (int off = 32; off >= 1; off >>= 1) mx = fmaxf(mx, __shfl_xor(mx, off, 64));
    float ex = expf(v - mx);
    float s2 = ex;
    #pragma unroll
    for (int off = 32; off >= 1; off >>= 1) s2 += __shfl_xor(s2, off, 64);
    out[(size_t)node * 64 + lane] = v - mx - logf(s2);
}

// ---------------------------------------------------------------------------

extern "C" void kernel_launch(void* const* d_in, const int* in_sizes, int n_in,
                              void* d_out, int out_size, void* d_ws, size_t ws_size,
                              hipStream_t stream) {
    const float* x     = (const float*)d_in[0];
    const int*   ei    = (const int*)d_in[1];
    const float* W1    = (const float*)d_in[2];
    const float* att1s = (const float*)d_in[3];
    const float* att1d = (const float*)d_in[4];
    const float* b1    = (const float*)d_in[5];
    const float* W2    = (const float*)d_in[6];
    const float* att2s = (const float*)d_in[7];
    const float* att2d = (const float*)d_in[8];
    const float* b2    = (const float*)d_in[9];
    float* out = (float*)d_out;

    const int N = N_NODES, E = N_EDGES;

    char* p = (char*)d_ws;
    auto take = [&](size_t bytes) {
        char* r = p;
        p += (bytes + 255) & ~(size_t)255;
        return (void*)r;
    };
    int*            head     = (int*)take((size_t)N * 2 * 4);                 // dual heads
    int*            deg      = (int*)take((size_t)N * 4);
    int*            rowstart = (int*)take((size_t)N * 4);
    int*            counter  = (int*)take(256);
    int2*           rec8     = (int2*)take((size_t)E * 8);
    int*            csr_src  = (int*)take((size_t)E * 4);
    unsigned short* w1b      = (unsigned short*)take(64 * 64 * 16);           // 64 KB
    unsigned short* w2b      = (unsigned short*)take(16 * 64 * 16);           // 16 KB
    unsigned short* h1b      = (unsigned short*)take((size_t)N * 128 * 2);    // bf16
    float*          a1s      = (float*)take((size_t)N * 8 * 4);               // reused a2s
    float*          a1d      = (float*)take((size_t)N * 8 * 4);               // reused a2d
    unsigned int*   h2b      = (unsigned int*)take((size_t)N * 64 * 4);       // packed bf16
    unsigned short* t2b      = (unsigned short*)take((size_t)N * 64 * 2);     // bf16
    float* a2s = a1s;
    float* a2d = a1d;

    hipMemsetAsync(head, 0xFF, (size_t)N * 2 * 4, stream);   // -1 sentinels
    hipMemsetAsync(counter, 0, 4, stream);

    prep_kernel<<<20, 256, 0, stream>>>(W1, W2, w1b, w2b);
    gemm1_link_kernel<<<FUSED_BLOCKS, 256, 0, stream>>>(
        x, (const short8*)w1b, att1s, att1d, h1b, a1s, a1d, ei, head, rec8);
    csr_build_kernel<<<(N + 255) / 256, 256, 0, stream>>>(head, rec8, rowstart, deg,
                                                          counter, csr_src, N);
    agg1_kernel<<<(N + 3) / 4, 256, 0, stream>>>(h1b, a1s, a1d, rowstart, deg, csr_src,
                                                 b1, h2b, N);
    gemm2_kernel<<<(N + 63) / 64, 256, 0, stream>>>((const short8*)h2b, (const short8*)w2b,
                                                    att2s, att2d, t2b, a2s, a2d, N);
    agg2_kernel<<<(N + 3) / 4, 256, 0, stream>>>(t2b, a2s, a2d, rowstart, deg, csr_src,
                                                 b2, out, N);
}

// Round 11
// 428.550 us; speedup vs baseline: 1.5051x; 1.0423x over previous
//
#include <hip/hip_runtime.h>
#include <math.h>

#define N_NODES 100000
#define N_EDGES 1600000
#define GEMM1_BLOCKS ((N_NODES + 63) / 64)        // 1563
#define NBKT 196                                  // ceil(100000 / 512)
#define PART_BLOCKS ((N_EDGES + 4095) / 4096)     // 391

typedef __attribute__((ext_vector_type(8))) short short8;    // 8 x bf16 bits
typedef __attribute__((ext_vector_type(4))) float floatx4;   // MFMA acc

__device__ __forceinline__ float lrelu(float v) {
    return (v > 0.f) ? v : 0.2f * v;
}

__device__ __forceinline__ unsigned short f2bf(float f) {
    unsigned int u = __float_as_uint(f);
    u += 0x7fff + ((u >> 16) & 1);   // round-to-nearest-even
    return (unsigned short)(u >> 16);
}

__device__ __forceinline__ float bflo(unsigned int u) { return __uint_as_float(u << 16); }
__device__ __forceinline__ float bfhi(unsigned int u) { return __uint_as_float(u & 0xffff0000u); }
__device__ __forceinline__ float bfs(unsigned short s) { return __uint_as_float(((unsigned int)s) << 16); }

// ---------------------------------------------------------------------------
// prep: swizzle W1/W2 into bf16 MFMA B-fragment order.
// ---------------------------------------------------------------------------
__global__ void prep_kernel(const float* __restrict__ W1, const float* __restrict__ W2,
                            unsigned short* __restrict__ w1b, unsigned short* __restrict__ w2b) {
    int idx = blockIdx.x * 256 + threadIdx.x;
    if (idx < 4096) {
        int lane = idx & 63;
        int ts = idx >> 6;
        int t = ts >> 3, ks = ts & 7;
        int quad = lane >> 4, l15 = lane & 15;
        int kbase = ks * 32 + quad * 8;
        unsigned short o[8];
        #pragma unroll
        for (int j = 0; j < 8; j++)
            o[j] = f2bf(W1[(size_t)(kbase + j) * 128 + t * 16 + l15]);
        uint4 pk;
        pk.x = o[0] | ((unsigned int)o[1] << 16);
        pk.y = o[2] | ((unsigned int)o[3] << 16);
        pk.z = o[4] | ((unsigned int)o[5] << 16);
        pk.w = o[6] | ((unsigned int)o[7] << 16);
        ((uint4*)w1b)[idx] = pk;
    } else if (idx < 4096 + 1024) {
        int idx2 = idx - 4096;
        int lane = idx2 & 63;
        int ts = idx2 >> 6;
        int t = ts >> 2, ks = ts & 3;
        int quad = lane >> 4, l15 = lane & 15;
        int kbase = ks * 32 + quad * 8;
        unsigned short o[8];
        #pragma unroll
        for (int j = 0; j < 8; j++)
            o[j] = f2bf(W2[(size_t)(kbase + j) * 64 + t * 16 + l15]);
        uint4 pk;
        pk.x = o[0] | ((unsigned int)o[1] << 16);
        pk.y = o[2] | ((unsigned int)o[3] << 16);
        pk.z = o[4] | ((unsigned int)o[5] << 16);
        pk.w = o[6] | ((unsigned int)o[7] << 16);
        ((uint4*)w2b)[idx2] = pk;
    }
}

// ---------------------------------------------------------------------------
// hist: per-block LDS histogram of dst>>9 -> global bkt_count (77k atomics
// total vs 1.6M in the old linked-list build).
// ---------------------------------------------------------------------------
__global__ void __launch_bounds__(256) hist_kernel(const int* __restrict__ ei,
                                                   int* __restrict__ bkt_count) {
    __shared__ int h[NBKT];
    for (int i = threadIdx.x; i < NBKT; i += 256) h[i] = 0;
    __syncthreads();
    int base = blockIdx.x * 4096;
    #pragma unroll
    for (int it = 0; it < 16; it++) {
        int e = base + it * 256 + (int)threadIdx.x;
        if (e < N_EDGES) atomicAdd(&h[ei[N_EDGES + e] >> 9], 1);
    }
    __syncthreads();
    for (int i = threadIdx.x; i < NBKT; i += 256)
        if (h[i]) atomicAdd(&bkt_count[i], h[i]);
}

// ---------------------------------------------------------------------------
// scan: exclusive scan of the 196 bucket counts -> bkt_base / bkt_cursor.
// ---------------------------------------------------------------------------
__global__ void scan_kernel(const int* __restrict__ bkt_count, int* __restrict__ bkt_base,
                            int* __restrict__ bkt_cursor) {
    __shared__ int ps[256];
    int tid = threadIdx.x;
    int v = (tid < NBKT) ? bkt_count[tid] : 0;
    ps[tid] = v;
    __syncthreads();
    for (int off = 1; off < 256; off <<= 1) {
        int t = (tid >= off) ? ps[tid - off] : 0;
        __syncthreads();
        ps[tid] += t;
        __syncthreads();
    }
    int excl = (tid > 0) ? ps[tid - 1] : 0;
    if (tid < NBKT) { bkt_base[tid] = excl; bkt_cursor[tid] = excl; }
    if (tid == NBKT) bkt_base[NBKT] = N_EDGES;
}

// ---------------------------------------------------------------------------
// part: bucket-partition edges by dst>>9. Each block: stage 4096 edges in
// regs (static idx), LDS histogram, ONE global atomicAdd per touched bucket
// to reserve a contiguous range, then write packed (src | dlow<<17) ints.
// Writes per bucket cluster into ~21-slot runs -> lines fill while L2-hot
// (fixes round-1 scatter's 107MB write blowup).
// ---------------------------------------------------------------------------
__global__ void __launch_bounds__(256) part_kernel(const int* __restrict__ ei,
                                                   int* __restrict__ bkt_cursor,
                                                   int* __restrict__ ebuf) {
    __shared__ int lcnt[NBKT];
    __shared__ int lbase[NBKT];
    for (int i = threadIdx.x; i < NBKT; i += 256) lcnt[i] = 0;
    __syncthreads();
    int base = blockIdx.x * 4096;
    int pk[16], bb[16];
    #pragma unroll
    for (int it = 0; it < 16; it++) {
        int e = base + it * 256 + (int)threadIdx.x;
        bb[it] = -1;
        pk[it] = 0;
        if (e < N_EDGES) {
            int s = ei[e];
            int d = ei[N_EDGES + e];
            bb[it] = d >> 9;
            pk[it] = s | ((d & 511) << 17);
            atomicAdd(&lcnt[bb[it]], 1);
        }
    }
    __syncthreads();
    for (int i = threadIdx.x; i < NBKT; i += 256) {
        int c = lcnt[i];
        lbase[i] = c ? atomicAdd(&bkt_cursor[i], c) : 0;
        lcnt[i] = 0;
    }
    __syncthreads();
    #pragma unroll
    for (int it = 0; it < 16; it++) {
        if (bb[it] >= 0) {
            int off = atomicAdd(&lcnt[bb[it]], 1);
            ebuf[lbase[bb[it]] + off] = pk[it];
        }
    }
}

// ---------------------------------------------------------------------------
// csr2: one block per bucket (~8200 edges, 512 nodes). Coalesced read ->
// 512-bin LDS histogram -> LDS scan -> EXACT rowstart/deg (zero global
// counter atomics) -> scatter csr_src inside a 33KB L2-hot window.
// ---------------------------------------------------------------------------
__global__ void __launch_bounds__(256) csr2_kernel(const int* __restrict__ ebuf,
                                                   const int* __restrict__ bkt_base,
                                                   int* __restrict__ rowstart,
                                                   int* __restrict__ deg,
                                                   int* __restrict__ csr_src) {
    __shared__ int h[512];
    __shared__ int cur[512];
    __shared__ int ps[256];
    const int b = blockIdx.x;
    const int s = bkt_base[b];
    const int e = bkt_base[b + 1];
    const int tid = threadIdx.x;
    h[tid] = 0;
    h[tid + 256] = 0;
    __syncthreads();
    for (int i = s + tid; i < e; i += 256)
        atomicAdd(&h[((unsigned)ebuf[i]) >> 17], 1);
    __syncthreads();
    int a0 = h[2 * tid], a1 = h[2 * tid + 1];
    ps[tid] = a0 + a1;
    __syncthreads();
    for (int off = 1; off < 256; off <<= 1) {
        int t = (tid >= off) ? ps[tid - off] : 0;
        __syncthreads();
        ps[tid] += t;
        __syncthreads();
    }
    int pbase = (tid > 0) ? ps[tid - 1] : 0;
    int n0 = b * 512 + 2 * tid;
    int n1 = n0 + 1;
    cur[2 * tid] = s + pbase;
    cur[2 * tid + 1] = s + pbase + a0;
    if (n0 < N_NODES) { rowstart[n0] = s + pbase; deg[n0] = a0; }
    if (n1 < N_NODES) { rowstart[n1] = s + pbase + a0; deg[n1] = a1; }
    __syncthreads();
    for (int i = s + tid; i < e; i += 256) {
        unsigned pkv = (unsigned)ebuf[i];
        int pos = atomicAdd(&cur[pkv >> 17], 1);
        csr_src[pos] = pkv & 0x1FFFF;
    }
}

// ---------------------------------------------------------------------------
// GEMM1 (MFMA bf16), pure — link role deleted. Round-2 proven inner form.
// ---------------------------------------------------------------------------
__global__ void __launch_bounds__(256) gemm1_kernel(
        const float* __restrict__ x, const short8* __restrict__ w1b,
        const float* __restrict__ att_s, const float* __restrict__ att_d,
        unsigned short* __restrict__ h1b, float* __restrict__ a1s, float* __restrict__ a1d) {
    const int gid = blockIdx.x;                     // 0..1562
    const int lane = threadIdx.x & 63;
    const int wv = threadIdx.x >> 6;
    const int quad = lane >> 4;
    const int l15 = lane & 15;
    const int M = N_NODES;

    const int rowA = gid * 64 + wv * 16 + l15;
    const bool rowAok = rowA < M;
    const float4* xrow4 = (const float4*)(x + (size_t)rowA * 256);

    floatx4 acc[8];
    #pragma unroll
    for (int t = 0; t < 8; t++) acc[t] = (floatx4){0.f, 0.f, 0.f, 0.f};

    #pragma unroll
    for (int ks = 0; ks < 8; ks++) {
        float4 p0, p1;
        if (rowAok) {
            p0 = xrow4[ks * 8 + quad * 2];
            p1 = xrow4[ks * 8 + quad * 2 + 1];
        } else {
            p0 = make_float4(0.f, 0.f, 0.f, 0.f);
            p1 = p0;
        }
        short8 af;
        af[0] = (short)f2bf(p0.x); af[1] = (short)f2bf(p0.y);
        af[2] = (short)f2bf(p0.z); af[3] = (short)f2bf(p0.w);
        af[4] = (short)f2bf(p1.x); af[5] = (short)f2bf(p1.y);
        af[6] = (short)f2bf(p1.z); af[7] = (short)f2bf(p1.w);
        #pragma unroll
        for (int t = 0; t < 8; t++) {
            short8 bf = w1b[(t * 8 + ks) * 64 + lane];
            acc[t] = __builtin_amdgcn_mfma_f32_16x16x32_bf16(af, bf, acc[t], 0, 0, 0);
        }
    }

    // Epilogue: C layout col = l15, row = quad*4 + r (tile t == head t).
    const int rowC0 = gid * 64 + wv * 16 + quad * 4;
    #pragma unroll
    for (int t = 0; t < 8; t++) {
        float asw = att_s[t * 16 + l15];
        float adw = att_d[t * 16 + l15];
        #pragma unroll
        for (int r = 0; r < 4; r++) {
            int grow = rowC0 + r;
            float c = acc[t][r];
            if (grow < M) h1b[(size_t)grow * 128 + t * 16 + l15] = f2bf(c);
            float ps = c * asw;
            float pd = c * adw;
            ps += __shfl_xor(ps, 1, 64); ps += __shfl_xor(ps, 2, 64);
            ps += __shfl_xor(ps, 4, 64); ps += __shfl_xor(ps, 8, 64);
            pd += __shfl_xor(pd, 1, 64); pd += __shfl_xor(pd, 2, 64);
            pd += __shfl_xor(pd, 4, 64); pd += __shfl_xor(pd, 8, 64);
            if (l15 == 0 && grow < M) { a1s[grow * 8 + t] = ps; a1d[grow * 8 + t] = pd; }
        }
    }
}

// ---------------------------------------------------------------------------
// agg1: one wave per dst node over CSR. 8-way unrolled (round-6 form).
// ---------------------------------------------------------------------------
__global__ void __launch_bounds__(256) agg1_kernel(
        const unsigned short* __restrict__ h1b, const float* __restrict__ a1s,
        const float* __restrict__ a1d, const int* __restrict__ rowstart,
        const int* __restrict__ deg, const int* __restrict__ csr_src,
        const float* __restrict__ b1, unsigned int* __restrict__ h2b, int n) {
    const int lane = threadIdx.x & 63;
    const int node = blockIdx.x * 4 + (threadIdx.x >> 6);
    if (node >= n) return;
    const int h = lane >> 3;
    const int start = rowstart[node];
    const int d = deg[node];
    const float ad = a1d[node * 8 + h];
    float l = 0.f, acc0 = 0.f, acc1 = 0.f;
    int i = 0;
    for (; i + 8 <= d; i += 8) {
        int s[8];
        float as[8];
        unsigned int u[8];
        #pragma unroll
        for (int k = 0; k < 8; k++) s[k] = csr_src[start + i + k];
        #pragma unroll
        for (int k = 0; k < 8; k++) as[k] = a1s[s[k] * 8 + h];
        #pragma unroll
        for (int k = 0; k < 8; k++)
            u[k] = *(const unsigned int*)(h1b + (size_t)s[k] * 128 + lane * 2);
        #pragma unroll
        for (int k = 0; k < 8; k++) {
            float e = __expf(lrelu(as[k] + ad));
            l += e;
            acc0 += e * bflo(u[k]);
            acc1 += e * bfhi(u[k]);
        }
    }
    for (; i + 4 <= d; i += 4) {
        int s[4];
        float as[4];
        unsigned int u[4];
        #pragma unroll
        for (int k = 0; k < 4; k++) s[k] = csr_src[start + i + k];
        #pragma unroll
        for (int k = 0; k < 4; k++) as[k] = a1s[s[k] * 8 + h];
        #pragma unroll
        for (int k = 0; k < 4; k++)
            u[k] = *(const unsigned int*)(h1b + (size_t)s[k] * 128 + lane * 2);
        #pragma unroll
        for (int k = 0; k < 4; k++) {
            float e = __expf(lrelu(as[k] + ad));
            l += e;
            acc0 += e * bflo(u[k]);
            acc1 += e * bfhi(u[k]);
        }
    }
    for (; i < d; i++) {
        int s0 = csr_src[start + i];
        float as0 = a1s[s0 * 8 + h];
        unsigned int u0 = *(const unsigned int*)(h1b + (size_t)s0 * 128 + lane * 2);
        float e0 = __expf(lrelu(as0 + ad));
        l += e0;
        acc0 += e0 * bflo(u0);
        acc1 += e0 * bfhi(u0);
    }
    float inv = 1.f / (l + 1e-16f);
    float v0 = acc0 * inv + b1[lane * 2];
    float v1 = acc1 * inv + b1[lane * 2 + 1];
    v0 = (v0 > 0.f) ? v0 : expm1f(v0);
    v1 = (v1 > 0.f) ? v1 : expm1f(v1);
    h2b[(size_t)node * 64 + lane] = (unsigned int)f2bf(v0) | ((unsigned int)f2bf(v1) << 16);
}

// ---------------------------------------------------------------------------
// GEMM2 (MFMA bf16): t2b = bf16(h2[N,128] @ W2[128,64]); fused a2s/a2d dots.
// ---------------------------------------------------------------------------
__global__ void __launch_bounds__(256) gemm2_kernel(
        const short8* __restrict__ h2f, const short8* __restrict__ w2b,
        const float* __restrict__ att_s, const float* __restrict__ att_d,
        unsigned short* __restrict__ t2b, float* __restrict__ a2s, float* __restrict__ a2d,
        int n) {
    const int lane = threadIdx.x & 63;
    const int wv = threadIdx.x >> 6;
    const int quad = lane >> 4;
    const int l15 = lane & 15;

    const int rowA = blockIdx.x * 64 + wv * 16 + l15;
    const bool rowAok = rowA < n;

    floatx4 acc[4];
    #pragma unroll
    for (int t = 0; t < 4; t++) acc[t] = (floatx4){0.f, 0.f, 0.f, 0.f};

    #pragma unroll
    for (int ks = 0; ks < 4; ks++) {
        short8 af = {0, 0, 0, 0, 0, 0, 0, 0};
        if (rowAok) af = h2f[(size_t)rowA * 16 + ks * 4 + quad];
        #pragma unroll
        for (int t = 0; t < 4; t++) {
            short8 bf = w2b[(t * 4 + ks) * 64 + lane];
            acc[t] = __builtin_amdgcn_mfma_f32_16x16x32_bf16(af, bf, acc[t], 0, 0, 0);
        }
    }

    const int rowC0 = blockIdx.x * 64 + wv * 16 + quad * 4;
    float asw[4], adw[4];
    #pragma unroll
    for (int t = 0; t < 4; t++) {
        asw[t] = att_s[t * 16 + l15];
        adw[t] = att_d[t * 16 + l15];
    }
    #pragma unroll
    for (int r = 0; r < 4; r++) {
        int grow = rowC0 + r;
        bool ok = grow < n;
        float ps = 0.f, pd = 0.f;
        #pragma unroll
        for (int t = 0; t < 4; t++) {
            float c = acc[t][r];
            if (ok) t2b[(size_t)grow * 64 + t * 16 + l15] = f2bf(c);
            ps += c * asw[t];
            pd += c * adw[t];
        }
        ps += __shfl_xor(ps, 1, 64); ps += __shfl_xor(ps, 2, 64);
        ps += __shfl_xor(ps, 4, 64); ps += __shfl_xor(ps, 8, 64);
        pd += __shfl_xor(pd, 1, 64); pd += __shfl_xor(pd, 2, 64);
        pd += __shfl_xor(pd, 4, 64); pd += __shfl_xor(pd, 8, 64);
        if (l15 == 0 && ok) { a2s[grow] = ps; a2d[grow] = pd; }
    }
}

// ---------------------------------------------------------------------------
// agg2: one wave per dst node over CSR. 8-way unrolled (round-6 form).
// Fused bias + log_softmax across the 64 lanes.
// ---------------------------------------------------------------------------
__global__ void __launch_bounds__(256) agg2_kernel(
        const unsigned short* __restrict__ t2b, const float* __restrict__ a2s,
        const float* __restrict__ a2d, const int* __restrict__ rowstart,
        const int* __restrict__ deg, const int* __restrict__ csr_src,
        const float* __restrict__ b2, float* __restrict__ out, int n) {
    const int lane = threadIdx.x & 63;
    const int node = blockIdx.x * 4 + (threadIdx.x >> 6);
    if (node >= n) return;
    const int start = rowstart[node];
    const int d = deg[node];
    const float ad = a2d[node];
    float l = 0.f, acc = 0.f;
    int i = 0;
    for (; i + 8 <= d; i += 8) {
        int s[8];
        float as[8];
        unsigned short u[8];
        #pragma unroll
        for (int k = 0; k < 8; k++) s[k] = csr_src[start + i + k];
        #pragma unroll
        for (int k = 0; k < 8; k++) as[k] = a2s[s[k]];
        #pragma unroll
        for (int k = 0; k < 8; k++) u[k] = t2b[(size_t)s[k] * 64 + lane];
        #pragma unroll
        for (int k = 0; k < 8; k++) {
            float e = __expf(lrelu(as[k] + ad));
            l += e;
            acc += e * bfs(u[k]);
        }
    }
    for (; i + 4 <= d; i += 4) {
        int s[4];
        float as[4];
        unsigned short u[4];
        #pragma unroll
        for (int k = 0; k < 4; k++) s[k] = csr_src[start + i + k];
        #pragma unroll
        for (int k = 0; k < 4; k++) as[k] = a2s[s[k]];
        #pragma unroll
        for (int k = 0; k < 4; k++) u[k] = t2b[(size_t)s[k] * 64 + lane];
        #pragma unroll
        for (int k = 0; k < 4; k++) {
            float e = __expf(lrelu(as[k] + ad));
            l += e;
            acc += e * bfs(u[k]);
        }
    }
    for (; i < d; i++) {
        int s0 = csr_src[start + i];
        float as0 = a2s[s0];
        unsigned short u0 = t2b[(size_t)s0 * 64 + lane];
        float e0 = __expf(lrelu(as0 + ad));
        l += e0;
        acc += e0 * bfs(u0);
    }
    float v = acc / (l + 1e-16f) + b2[lane];
    float mx = v;
    #pragma unroll
    for (int off = 32; off >= 1; off >>= 1) mx = fmaxf(mx, __shfl_xor(mx, off, 64));
    float ex = expf(v - mx);
    float s2 = ex;
    #pragma unroll
    for (int off = 32; off >= 1; off >>= 1) s2 += __shfl_xor(s2, off, 64);
    out[(size_t)node * 64 + lane] = v - mx - logf(s2);
}

// ---------------------------------------------------------------------------

extern "C" void kernel_launch(void* const* d_in, const int* in_sizes, int n_in,
                              void* d_out, int out_size, void* d_ws, size_t ws_size,
                              hipStream_t stream) {
    const float* x     = (const float*)d_in[0];
    const int*   ei    = (const int*)d_in[1];
    const float* W1    = (const float*)d_in[2];
    const float* att1s = (const float*)d_in[3];
    const float* att1d = (const float*)d_in[4];
    const float* b1    = (const float*)d_in[5];
    const float* W2    = (const float*)d_in[6];
    const float* att2s = (const float*)d_in[7];
    const float* att2d = (const float*)d_in[8];
    const float* b2    = (const float*)d_in[9];
    float* out = (float*)d_out;

    const int N = N_NODES, E = N_EDGES;

    char* p = (char*)d_ws;
    auto take = [&](size_t bytes) {
        char* r = p;
        p += (bytes + 255) & ~(size_t)255;
        return (void*)r;
    };
    int*            bkt_count  = (int*)take(256 * 4);
    int*            bkt_base   = (int*)take(257 * 4);
    int*            bkt_cursor = (int*)take(256 * 4);
    int*            ebuf       = (int*)take((size_t)E * 4);
    int*            deg        = (int*)take((size_t)N * 4);
    int*            rowstart   = (int*)take((size_t)N * 4);
    int*            csr_src    = (int*)take((size_t)E * 4);
    unsigned short* w1b        = (unsigned short*)take(64 * 64 * 16);           // 64 KB
    unsigned short* w2b        = (unsigned short*)take(16 * 64 * 16);           // 16 KB
    unsigned short* h1b        = (unsigned short*)take((size_t)N * 128 * 2);    // bf16
    float*          a1s        = (float*)take((size_t)N * 8 * 4);               // reused a2s
    float*          a1d        = (float*)take((size_t)N * 8 * 4);               // reused a2d
    unsigned int*   h2b        = (unsigned int*)take((size_t)N * 64 * 4);       // packed bf16
    unsigned short* t2b        = (unsigned short*)take((size_t)N * 64 * 2);     // bf16
    float* a2s = a1s;
    float* a2d = a1d;

    hipMemsetAsync(bkt_count, 0, 256 * 4, stream);

    prep_kernel<<<20, 256, 0, stream>>>(W1, W2, w1b, w2b);
    hist_kernel<<<PART_BLOCKS, 256, 0, stream>>>(ei, bkt_count);
    scan_kernel<<<1, 256, 0, stream>>>(bkt_count, bkt_base, bkt_cursor);
    part_kernel<<<PART_BLOCKS, 256, 0, stream>>>(ei, bkt_cursor, ebuf);
    csr2_kernel<<<NBKT, 256, 0, stream>>>(ebuf, bkt_base, rowstart, deg, csr_src);
    gemm1_kernel<<<GEMM1_BLOCKS, 256, 0, stream>>>(
        x, (const short8*)w1b, att1s, att1d, h1b, a1s, a1d);
    agg1_kernel<<<(N + 3) / 4, 256, 0, stream>>>(h1b, a1s, a1d, rowstart, deg, csr_src,
                                                 b1, h2b, N);
    gemm2_kernel<<<(N + 63) / 64, 256, 0, stream>>>((const short8*)h2b, (const short8*)w2b,
                                                    att2s, att2d, t2b, a2s, a2d, N);
    agg2_kernel<<<(N + 3) / 4, 256, 0, stream>>>(t2b, a2s, a2d, rowstart, deg, csr_src,
                                                 b2, out, N);
}

// Round 12
// 417.176 us; speedup vs baseline: 1.5462x; 1.0273x over previous
//
#include <hip/hip_runtime.h>
#include <math.h>

#define N_NODES 100000
#define N_EDGES 1600000
#define GEMM1_BLOCKS ((N_NODES + 63) / 64)        // 1563
#define NBKT 196                                  // ceil(100000 / 512)
#define PART_BLOCKS ((N_EDGES + 4095) / 4096)     // 391
// gemm1 block distribution across the three sort-stage kernels:
#define GEMM_K1 400                               // in hist kernel
#define GEMM_K3 700                               // in part kernel
#define GEMM_K4 (GEMM1_BLOCKS - GEMM_K1 - GEMM_K3)// 463, in csr2 kernel

typedef __attribute__((ext_vector_type(8))) short short8;    // 8 x bf16 bits
typedef __attribute__((ext_vector_type(4))) float floatx4;   // MFMA acc

__device__ __forceinline__ float lrelu(float v) {
    return (v > 0.f) ? v : 0.2f * v;
}

__device__ __forceinline__ unsigned short f2bf(float f) {
    unsigned int u = __float_as_uint(f);
    u += 0x7fff + ((u >> 16) & 1);   // round-to-nearest-even
    return (unsigned short)(u >> 16);
}

__device__ __forceinline__ float bflo(unsigned int u) { return __uint_as_float(u << 16); }
__device__ __forceinline__ float bfhi(unsigned int u) { return __uint_as_float(u & 0xffff0000u); }
__device__ __forceinline__ float bfs(unsigned short s) { return __uint_as_float(((unsigned int)s) << 16); }

// ---------------------------------------------------------------------------
// GEMM1 role body (round-2 proven form), shared by the fused kernels.
// ---------------------------------------------------------------------------
__device__ __forceinline__ void gemm1_body(
        int gid, const float* __restrict__ x, const short8* __restrict__ w1b,
        const float* __restrict__ att_s, const float* __restrict__ att_d,
        unsigned short* __restrict__ h1b, float* __restrict__ a1s, float* __restrict__ a1d) {
    const int lane = threadIdx.x & 63;
    const int wv = threadIdx.x >> 6;
    const int quad = lane >> 4;
    const int l15 = lane & 15;
    const int M = N_NODES;

    const int rowA = gid * 64 + wv * 16 + l15;
    const bool rowAok = rowA < M;
    const float4* xrow4 = (const float4*)(x + (size_t)rowA * 256);

    floatx4 acc[8];
    #pragma unroll
    for (int t = 0; t < 8; t++) acc[t] = (floatx4){0.f, 0.f, 0.f, 0.f};

    #pragma unroll
    for (int ks = 0; ks < 8; ks++) {
        float4 p0, p1;
        if (rowAok) {
            p0 = xrow4[ks * 8 + quad * 2];
            p1 = xrow4[ks * 8 + quad * 2 + 1];
        } else {
            p0 = make_float4(0.f, 0.f, 0.f, 0.f);
            p1 = p0;
        }
        short8 af;
        af[0] = (short)f2bf(p0.x); af[1] = (short)f2bf(p0.y);
        af[2] = (short)f2bf(p0.z); af[3] = (short)f2bf(p0.w);
        af[4] = (short)f2bf(p1.x); af[5] = (short)f2bf(p1.y);
        af[6] = (short)f2bf(p1.z); af[7] = (short)f2bf(p1.w);
        #pragma unroll
        for (int t = 0; t < 8; t++) {
            short8 bf = w1b[(t * 8 + ks) * 64 + lane];
            acc[t] = __builtin_amdgcn_mfma_f32_16x16x32_bf16(af, bf, acc[t], 0, 0, 0);
        }
    }

    const int rowC0 = gid * 64 + wv * 16 + quad * 4;
    #pragma unroll
    for (int t = 0; t < 8; t++) {
        float asw = att_s[t * 16 + l15];
        float adw = att_d[t * 16 + l15];
        #pragma unroll
        for (int r = 0; r < 4; r++) {
            int grow = rowC0 + r;
            float c = acc[t][r];
            if (grow < M) h1b[(size_t)grow * 128 + t * 16 + l15] = f2bf(c);
            float ps = c * asw;
            float pd = c * adw;
            ps += __shfl_xor(ps, 1, 64); ps += __shfl_xor(ps, 2, 64);
            ps += __shfl_xor(ps, 4, 64); ps += __shfl_xor(ps, 8, 64);
            pd += __shfl_xor(pd, 1, 64); pd += __shfl_xor(pd, 2, 64);
            pd += __shfl_xor(pd, 4, 64); pd += __shfl_xor(pd, 8, 64);
            if (l15 == 0 && grow < M) { a1s[grow * 8 + t] = ps; a1d[grow * 8 + t] = pd; }
        }
    }
}

// ---------------------------------------------------------------------------
// prep: swizzle W1/W2 into bf16 MFMA B-fragment order.
// ---------------------------------------------------------------------------
__global__ void prep_kernel(const float* __restrict__ W1, const float* __restrict__ W2,
                            unsigned short* __restrict__ w1b, unsigned short* __restrict__ w2b) {
    int idx = blockIdx.x * 256 + threadIdx.x;
    if (idx < 4096) {
        int lane = idx & 63;
        int ts = idx >> 6;
        int t = ts >> 3, ks = ts & 7;
        int quad = lane >> 4, l15 = lane & 15;
        int kbase = ks * 32 + quad * 8;
        unsigned short o[8];
        #pragma unroll
        for (int j = 0; j < 8; j++)
            o[j] = f2bf(W1[(size_t)(kbase + j) * 128 + t * 16 + l15]);
        uint4 pk;
        pk.x = o[0] | ((unsigned int)o[1] << 16);
        pk.y = o[2] | ((unsigned int)o[3] << 16);
        pk.z = o[4] | ((unsigned int)o[5] << 16);
        pk.w = o[6] | ((unsigned int)o[7] << 16);
        ((uint4*)w1b)[idx] = pk;
    } else if (idx < 4096 + 1024) {
        int idx2 = idx - 4096;
        int lane = idx2 & 63;
        int ts = idx2 >> 6;
        int t = ts >> 2, ks = ts & 3;
        int quad = lane >> 4, l15 = lane & 15;
        int kbase = ks * 32 + quad * 8;
        unsigned short o[8];
        #pragma unroll
        for (int j = 0; j < 8; j++)
            o[j] = f2bf(W2[(size_t)(kbase + j) * 64 + t * 16 + l15]);
        uint4 pk;
        pk.x = o[0] | ((unsigned int)o[1] << 16);
        pk.y = o[2] | ((unsigned int)o[3] << 16);
        pk.z = o[4] | ((unsigned int)o[5] << 16);
        pk.w = o[6] | ((unsigned int)o[7] << 16);
        ((uint4*)w2b)[idx2] = pk;
    }
}

// ---------------------------------------------------------------------------
// K1: hist (blocks 0..390) || gemm1 gids 0..GEMM_K1-1. Chains independent.
// ---------------------------------------------------------------------------
__global__ void __launch_bounds__(256) hist_gemm_kernel(
        const int* __restrict__ ei, int* __restrict__ bkt_count,
        const float* __restrict__ x, const short8* __restrict__ w1b,
        const float* __restrict__ att_s, const float* __restrict__ att_d,
        unsigned short* __restrict__ h1b, float* __restrict__ a1s, float* __restrict__ a1d) {
    const int bid = blockIdx.x;
    if (bid >= PART_BLOCKS) {
        gemm1_body(bid - PART_BLOCKS, x, w1b, att_s, att_d, h1b, a1s, a1d);
        return;
    }
    __shared__ int h[NBKT];
    for (int i = threadIdx.x; i < NBKT; i += 256) h[i] = 0;
    __syncthreads();
    int base = bid * 4096;
    #pragma unroll
    for (int it = 0; it < 16; it++) {
        int e = base + it * 256 + (int)threadIdx.x;
        if (e < N_EDGES) atomicAdd(&h[ei[N_EDGES + e] >> 9], 1);
    }
    __syncthreads();
    for (int i = threadIdx.x; i < NBKT; i += 256)
        if (h[i]) atomicAdd(&bkt_count[i], h[i]);
}

// ---------------------------------------------------------------------------
// scan: exclusive scan of the 196 bucket counts -> bkt_base / bkt_cursor.
// ---------------------------------------------------------------------------
__global__ void scan_kernel(const int* __restrict__ bkt_count, int* __restrict__ bkt_base,
                            int* __restrict__ bkt_cursor) {
    __shared__ int ps[256];
    int tid = threadIdx.x;
    int v = (tid < NBKT) ? bkt_count[tid] : 0;
    ps[tid] = v;
    __syncthreads();
    for (int off = 1; off < 256; off <<= 1) {
        int t = (tid >= off) ? ps[tid - off] : 0;
        __syncthreads();
        ps[tid] += t;
        __syncthreads();
    }
    int excl = (tid > 0) ? ps[tid - 1] : 0;
    if (tid < NBKT) { bkt_base[tid] = excl; bkt_cursor[tid] = excl; }
    if (tid == NBKT) bkt_base[NBKT] = N_EDGES;
}

// ---------------------------------------------------------------------------
// K3: part (blocks 0..390) || gemm1 gids GEMM_K1..GEMM_K1+GEMM_K3-1.
// part: stage 4096 edges in regs, LDS histogram, one global atomic per
// touched bucket, write packed (src | dlow<<17).
// ---------------------------------------------------------------------------
__global__ void __launch_bounds__(256) part_gemm_kernel(
        const int* __restrict__ ei, int* __restrict__ bkt_cursor, int* __restrict__ ebuf,
        const float* __restrict__ x, const short8* __restrict__ w1b,
        const float* __restrict__ att_s, const float* __restrict__ att_d,
        unsigned short* __restrict__ h1b, float* __restrict__ a1s, float* __restrict__ a1d) {
    const int bid = blockIdx.x;
    if (bid >= PART_BLOCKS) {
        gemm1_body(bid - PART_BLOCKS + GEMM_K1, x, w1b, att_s, att_d, h1b, a1s, a1d);
        return;
    }
    __shared__ int lcnt[NBKT];
    __shared__ int lbase[NBKT];
    for (int i = threadIdx.x; i < NBKT; i += 256) lcnt[i] = 0;
    __syncthreads();
    int base = bid * 4096;
    int pk[16], bb[16];
    #pragma unroll
    for (int it = 0; it < 16; it++) {
        int e = base + it * 256 + (int)threadIdx.x;
        bb[it] = -1;
        pk[it] = 0;
        if (e < N_EDGES) {
            int s = ei[e];
            int d = ei[N_EDGES + e];
            bb[it] = d >> 9;
            pk[it] = s | ((d & 511) << 17);
            atomicAdd(&lcnt[bb[it]], 1);
        }
    }
    __syncthreads();
    for (int i = threadIdx.x; i < NBKT; i += 256) {
        int c = lcnt[i];
        lbase[i] = c ? atomicAdd(&bkt_cursor[i], c) : 0;
        lcnt[i] = 0;
    }
    __syncthreads();
    #pragma unroll
    for (int it = 0; it < 16; it++) {
        if (bb[it] >= 0) {
            int off = atomicAdd(&lcnt[bb[it]], 1);
            ebuf[lbase[bb[it]] + off] = pk[it];
        }
    }
}

// ---------------------------------------------------------------------------
// K4: csr2 (blocks 0..195) || gemm1 gids GEMM_K1+GEMM_K3..1562.
// csr2: coalesced read -> 512-bin LDS hist -> LDS scan -> exact rowstart/deg
// -> scatter csr_src inside a 33KB L2-hot window.
// ---------------------------------------------------------------------------
__global__ void __launch_bounds__(256) csr2_gemm_kernel(
        const int* __restrict__ ebuf, const int* __restrict__ bkt_base,
        int* __restrict__ rowstart, int* __restrict__ deg, int* __restrict__ csr_src,
        const float* __restrict__ x, const short8* __restrict__ w1b,
        const float* __restrict__ att_s, const float* __restrict__ att_d,
        unsigned short* __restrict__ h1b, float* __restrict__ a1s, float* __restrict__ a1d) {
    const int bid = blockIdx.x;
    if (bid >= NBKT) {
        gemm1_body(bid - NBKT + GEMM_K1 + GEMM_K3, x, w1b, att_s, att_d, h1b, a1s, a1d);
        return;
    }
    __shared__ int h[512];
    __shared__ int cur[512];
    __shared__ int ps[256];
    const int b = bid;
    const int s = bkt_base[b];
    const int e = bkt_base[b + 1];
    const int tid = threadIdx.x;
    h[tid] = 0;
    h[tid + 256] = 0;
    __syncthreads();
    for (int i = s + tid; i < e; i += 256)
        atomicAdd(&h[((unsigned)ebuf[i]) >> 17], 1);
    __syncthreads();
    int a0 = h[2 * tid], a1 = h[2 * tid + 1];
    ps[tid] = a0 + a1;
    __syncthreads();
    for (int off = 1; off < 256; off <<= 1) {
        int t = (tid >= off) ? ps[tid - off] : 0;
        __syncthreads();
        ps[tid] += t;
        __syncthreads();
    }
    int pbase = (tid > 0) ? ps[tid - 1] : 0;
    int n0 = b * 512 + 2 * tid;
    int n1 = n0 + 1;
    cur[2 * tid] = s + pbase;
    cur[2 * tid + 1] = s + pbase + a0;
    if (n0 < N_NODES) { rowstart[n0] = s + pbase; deg[n0] = a0; }
    if (n1 < N_NODES) { rowstart[n1] = s + pbase + a0; deg[n1] = a1; }
    __syncthreads();
    for (int i = s + tid; i < e; i += 256) {
        unsigned pkv = (unsigned)ebuf[i];
        int pos = atomicAdd(&cur[pkv >> 17], 1);
        csr_src[pos] = pkv & 0x1FFFF;
    }
}

// ---------------------------------------------------------------------------
// agg1: one wave per dst node over CSR. 8-way unrolled (round-6 form).
// ---------------------------------------------------------------------------
__global__ void __launch_bounds__(256) agg1_kernel(
        const unsigned short* __restrict__ h1b, const float* __restrict__ a1s,
        const float* __restrict__ a1d, const int* __restrict__ rowstart,
        const int* __restrict__ deg, const int* __restrict__ csr_src,
        const float* __restrict__ b1, unsigned int* __restrict__ h2b, int n) {
    const int lane = threadIdx.x & 63;
    const int node = blockIdx.x * 4 + (threadIdx.x >> 6);
    if (node >= n) return;
    const int h = lane >> 3;
    const int start = rowstart[node];
    const int d = deg[node];
    const float ad = a1d[node * 8 + h];
    float l = 0.f, acc0 = 0.f, acc1 = 0.f;
    int i = 0;
    for (; i + 8 <= d; i += 8) {
        int s[8];
        float as[8];
        unsigned int u[8];
        #pragma unroll
        for (int k = 0; k < 8; k++) s[k] = csr_src[start + i + k];
        #pragma unroll
        for (int k = 0; k < 8; k++) as[k] = a1s[s[k] * 8 + h];
        #pragma unroll
        for (int k = 0; k < 8; k++)
            u[k] = *(const unsigned int*)(h1b + (size_t)s[k] * 128 + lane * 2);
        #pragma unroll
        for (int k = 0; k < 8; k++) {
            float e = __expf(lrelu(as[k] + ad));
            l += e;
            acc0 += e * bflo(u[k]);
            acc1 += e * bfhi(u[k]);
        }
    }
    for (; i + 4 <= d; i += 4) {
        int s[4];
        float as[4];
        unsigned int u[4];
        #pragma unroll
        for (int k = 0; k < 4; k++) s[k] = csr_src[start + i + k];
        #pragma unroll
        for (int k = 0; k < 4; k++) as[k] = a1s[s[k] * 8 + h];
        #pragma unroll
        for (int k = 0; k < 4; k++)
            u[k] = *(const unsigned int*)(h1b + (size_t)s[k] * 128 + lane * 2);
        #pragma unroll
        for (int k = 0; k < 4; k++) {
            float e = __expf(lrelu(as[k] + ad));
            l += e;
            acc0 += e * bflo(u[k]);
            acc1 += e * bfhi(u[k]);
        }
    }
    for (; i < d; i++) {
        int s0 = csr_src[start + i];
        float as0 = a1s[s0 * 8 + h];
        unsigned int u0 = *(const unsigned int*)(h1b + (size_t)s0 * 128 + lane * 2);
        float e0 = __expf(lrelu(as0 + ad));
        l += e0;
        acc0 += e0 * bflo(u0);
        acc1 += e0 * bfhi(u0);
    }
    float inv = 1.f / (l + 1e-16f);
    float v0 = acc0 * inv + b1[lane * 2];
    float v1 = acc1 * inv + b1[lane * 2 + 1];
    v0 = (v0 > 0.f) ? v0 : expm1f(v0);
    v1 = (v1 > 0.f) ? v1 : expm1f(v1);
    h2b[(size_t)node * 64 + lane] = (unsigned int)f2bf(v0) | ((unsigned int)f2bf(v1) << 16);
}

// ---------------------------------------------------------------------------
// GEMM2 (MFMA bf16): t2b = bf16(h2[N,128] @ W2[128,64]); fused a2s/a2d dots.
// ---------------------------------------------------------------------------
__global__ void __launch_bounds__(256) gemm2_kernel(
        const short8* __restrict__ h2f, const short8* __restrict__ w2b,
        const float* __restrict__ att_s, const float* __restrict__ att_d,
        unsigned short* __restrict__ t2b, float* __restrict__ a2s, float* __restrict__ a2d,
        int n) {
    const int lane = threadIdx.x & 63;
    const int wv = threadIdx.x >> 6;
    const int quad = lane >> 4;
    const int l15 = lane & 15;

    const int rowA = blockIdx.x * 64 + wv * 16 + l15;
    const bool rowAok = rowA < n;

    floatx4 acc[4];
    #pragma unroll
    for (int t = 0; t < 4; t++) acc[t] = (floatx4){0.f, 0.f, 0.f, 0.f};

    #pragma unroll
    for (int ks = 0; ks < 4; ks++) {
        short8 af = {0, 0, 0, 0, 0, 0, 0, 0};
        if (rowAok) af = h2f[(size_t)rowA * 16 + ks * 4 + quad];
        #pragma unroll
        for (int t = 0; t < 4; t++) {
            short8 bf = w2b[(t * 4 + ks) * 64 + lane];
            acc[t] = __builtin_amdgcn_mfma_f32_16x16x32_bf16(af, bf, acc[t], 0, 0, 0);
        }
    }

    const int rowC0 = blockIdx.x * 64 + wv * 16 + quad * 4;
    float asw[4], adw[4];
    #pragma unroll
    for (int t = 0; t < 4; t++) {
        asw[t] = att_s[t * 16 + l15];
        adw[t] = att_d[t * 16 + l15];
    }
    #pragma unroll
    for (int r = 0; r < 4; r++) {
        int grow = rowC0 + r;
        bool ok = grow < n;
        float ps = 0.f, pd = 0.f;
        #pragma unroll
        for (int t = 0; t < 4; t++) {
            float c = acc[t][r];
            if (ok) t2b[(size_t)grow * 64 + t * 16 + l15] = f2bf(c);
            ps += c * asw[t];
            pd += c * adw[t];
        }
        ps += __shfl_xor(ps, 1, 64); ps += __shfl_xor(ps, 2, 64);
        ps += __shfl_xor(ps, 4, 64); ps += __shfl_xor(ps, 8, 64);
        pd += __shfl_xor(pd, 1, 64); pd += __shfl_xor(pd, 2, 64);
        pd += __shfl_xor(pd, 4, 64); pd += __shfl_xor(pd, 8, 64);
        if (l15 == 0 && ok) { a2s[grow] = ps; a2d[grow] = pd; }
    }
}

// ---------------------------------------------------------------------------
// agg2: one wave per dst node over CSR. 8-way unrolled (round-6 form).
// Fused bias + log_softmax across the 64 lanes.
// ---------------------------------------------------------------------------
__global__ void __launch_bounds__(256) agg2_kernel(
        const unsigned short* __restrict__ t2b, const float* __restrict__ a2s,
        const float* __restrict__ a2d, const int* __restrict__ rowstart,
        const int* __restrict__ deg, const int* __restrict__ csr_src,
        const float* __restrict__ b2, float* __restrict__ out, int n) {
    const int lane = threadIdx.x & 63;
    const int node = blockIdx.x * 4 + (threadIdx.x >> 6);
    if (node >= n) return;
    const int start = rowstart[node];
    const int d = deg[node];
    const float ad = a2d[node];
    float l = 0.f, acc = 0.f;
    int i = 0;
    for (; i + 8 <= d; i += 8) {
        int s[8];
        float as[8];
        unsigned short u[8];
        #pragma unroll
        for (int k = 0; k < 8; k++) s[k] = csr_src[start + i + k];
        #pragma unroll
        for (int k = 0; k < 8; k++) as[k] = a2s[s[k]];
        #pragma unroll
        for (int k = 0; k < 8; k++) u[k] = t2b[(size_t)s[k] * 64 + lane];
        #pragma unroll
        for (int k = 0; k < 8; k++) {
            float e = __expf(lrelu(as[k] + ad));
            l += e;
            acc += e * bfs(u[k]);
        }
    }
    for (; i + 4 <= d; i += 4) {
        int s[4];
        float as[4];
        unsigned short u[4];
        #pragma unroll
        for (int k = 0; k < 4; k++) s[k] = csr_src[start + i + k];
        #pragma unroll
        for (int k = 0; k < 4; k++) as[k] = a2s[s[k]];
        #pragma unroll
        for (int k = 0; k < 4; k++) u[k] = t2b[(size_t)s[k] * 64 + lane];
        #pragma unroll
        for (int k = 0; k < 4; k++) {
            float e = __expf(lrelu(as[k] + ad));
            l += e;
            acc += e * bfs(u[k]);
        }
    }
    for (; i < d; i++) {
        int s0 = csr_src[start + i];
        float as0 = a2s[s0];
        unsigned short u0 = t2b[(size_t)s0 * 64 + lane];
        float e0 = __expf(lrelu(as0 + ad));
        l += e0;
        acc += e0 * bfs(u0);
    }
    float v = acc / (l + 1e-16f) + b2[lane];
    float mx = v;
    #pragma unroll
    for (int off = 32; off >= 1; off >>= 1) mx = fmaxf(mx, __shfl_xor(mx, off, 64));
    float ex = expf(v - mx);
    float s2 = ex;
    #pragma unroll
    for (int off = 32; off >= 1; off >>= 1) s2 += __shfl_xor(s2, off, 64);
    out[(size_t)node * 64 + lane] = v - mx - logf(s2);
}

// ---------------------------------------------------------------------------

extern "C" void kernel_launch(void* const* d_in, const int* in_sizes, int n_in,
                              void* d_out, int out_size, void* d_ws, size_t ws_size,
                              hipStream_t stream) {
    const float* x     = (const float*)d_in[0];
    const int*   ei    = (const int*)d_in[1];
    const float* W1    = (const float*)d_in[2];
    const float* att1s = (const float*)d_in[3];
    const float* att1d = (const float*)d_in[4];
    const float* b1    = (const float*)d_in[5];
    const float* W2    = (const float*)d_in[6];
    const float* att2s = (const float*)d_in[7];
    const float* att2d = (const float*)d_in[8];
    const float* b2    = (const float*)d_in[9];
    float* out = (float*)d_out;

    const int N = N_NODES, E = N_EDGES;

    char* p = (char*)d_ws;
    auto take = [&](size_t bytes) {
        char* r = p;
        p += (bytes + 255) & ~(size_t)255;
        return (void*)r;
    };
    int*            bkt_count  = (int*)take(256 * 4);
    int*            bkt_base   = (int*)take(257 * 4);
    int*            bkt_cursor = (int*)take(256 * 4);
    int*            ebuf       = (int*)take((size_t)E * 4);
    int*            deg        = (int*)take((size_t)N * 4);
    int*            rowstart   = (int*)take((size_t)N * 4);
    int*            csr_src    = (int*)take((size_t)E * 4);
    unsigned short* w1b        = (unsigned short*)take(64 * 64 * 16);           // 64 KB
    unsigned short* w2b        = (unsigned short*)take(16 * 64 * 16);           // 16 KB
    unsigned short* h1b        = (unsigned short*)take((size_t)N * 128 * 2);    // bf16
    float*          a1s        = (float*)take((size_t)N * 8 * 4);               // reused a2s
    float*          a1d        = (float*)take((size_t)N * 8 * 4);               // reused a2d
    unsigned int*   h2b        = (unsigned int*)take((size_t)N * 64 * 4);       // packed bf16
    unsigned short* t2b        = (unsigned short*)take((size_t)N * 64 * 2);     // bf16
    float* a2s = a1s;
    float* a2d = a1d;

    hipMemsetAsync(bkt_count, 0, 256 * 4, stream);

    prep_kernel<<<20, 256, 0, stream>>>(W1, W2, w1b, w2b);
    hist_gemm_kernel<<<PART_BLOCKS + GEMM_K1, 256, 0, stream>>>(
        ei, bkt_count, x, (const short8*)w1b, att1s, att1d, h1b, a1s, a1d);
    scan_kernel<<<1, 256, 0, stream>>>(bkt_count, bkt_base, bkt_cursor);
    part_gemm_kernel<<<PART_BLOCKS + GEMM_K3, 256, 0, stream>>>(
        ei, bkt_cursor, ebuf, x, (const short8*)w1b, att1s, att1d, h1b, a1s, a1d);
    csr2_gemm_kernel<<<NBKT + GEMM_K4, 256, 0, stream>>>(
        ebuf, bkt_base, rowstart, deg, csr_src,
        x, (const short8*)w1b, att1s, att1d, h1b, a1s, a1d);
    agg1_kernel<<<(N + 3) / 4, 256, 0, stream>>>(h1b, a1s, a1d, rowstart, deg, csr_src,
                                                 b1, h2b, N);
    gemm2_kernel<<<(N + 63) / 64, 256, 0, stream>>>((const short8*)h2b, (const short8*)w2b,
                                                    att2s, att2d, t2b, a2s, a2d, N);
    agg2_kernel<<<(N + 3) / 4, 256, 0, stream>>>(t2b, a2s, a2d, rowstart, deg, csr_src,
                                                 b2, out, N);
}